// Round 10
// baseline (481.542 us; speedup 1.0000x reference)
//
#include <hip/hip_runtime.h>
#include <hip/hip_bf16.h>

#define USER_NUM 50000
#define ITEM_NUM 20000
#define NNODE    70000
#define DD       64
#define CHUNK    1024
#define NCHUNK   ((NNODE + CHUNK - 1) / CHUNK)   // 69
#define GROWS    (NNODE / 8)                     // 8750 rows per coarse group
#define APB      1024                            // append: edges per block
#define NS2      128                             // scatter2: stripes per group

__device__ __forceinline__ const float* feat_row(const float* __restrict__ ue,
                                                 const float* __restrict__ ie, int n) {
    return (n < USER_NUM) ? (ue + (size_t)n * DD)
                          : (ie + (size_t)(n - USER_NUM) * DD);
}

// ---- CSR build -------------------------------------------------------------

__global__ __launch_bounds__(256) void hist_kernel(const int* __restrict__ erow,
                                                   int* __restrict__ cnt, int E) {
    const int stride = gridDim.x * blockDim.x;
    for (int e = blockIdx.x * blockDim.x + threadIdx.x; e < E; e += stride)
        atomicAdd(&cnt[erow[e]], 1);
}

// Phase 1: per-chunk sums (coalesced strided loads + wave/block reduce).
__global__ __launch_bounds__(256) void chunksum_kernel(const int* __restrict__ cnt,
                                                       int* __restrict__ csum) {
    __shared__ int red[4];
    const int c = blockIdx.x;
    const int t = threadIdx.x;
    int s = 0;
#pragma unroll
    for (int i = 0; i < 4; ++i) {
        const int idx = c * CHUNK + t + 256 * i;
        s += (idx < NNODE) ? cnt[idx] : 0;
    }
#pragma unroll
    for (int off = 32; off; off >>= 1) s += __shfl_down(s, off);
    if ((t & 63) == 0) red[t >> 6] = s;
    __syncthreads();
    if (t == 0) csum[c] = red[0] + red[1] + red[2] + red[3];
}

// Phase 2: exclusive scan of the 69 chunk sums (one tiny block).
__global__ __launch_bounds__(128) void scan_small_kernel(const int* __restrict__ csum,
                                                         int* __restrict__ coff) {
    __shared__ int s[128];
    const int t = threadIdx.x;
    const int v = (t < NCHUNK) ? csum[t] : 0;
    s[t] = v;
    __syncthreads();
    for (int off = 1; off < 128; off <<= 1) {
        const int val = s[t];
        const int add = (t >= off) ? s[t - off] : 0;
        __syncthreads();
        s[t] = val + add;
        __syncthreads();
    }
    if (t < NCHUNK) coff[t] = s[t] - v;
}

// Phase 3: per-chunk fill: dwordx4 loads, block scan, write base AND cursor.
__global__ __launch_bounds__(256) void fill_kernel(const int* __restrict__ cnt,
                                                   const int* __restrict__ coff,
                                                   int* __restrict__ base,
                                                   int* __restrict__ cursor) {
    __shared__ int sp[256];
    const int c  = blockIdx.x;
    const int t  = threadIdx.x;
    const int g0 = c * CHUNK + t * 4;
    int v[4];
#pragma unroll
    for (int i = 0; i < 4; ++i) v[i] = (g0 + i < NNODE) ? cnt[g0 + i] : 0;
    const int s = ((v[0] + v[1]) + (v[2] + v[3]));
    sp[t] = s;
    __syncthreads();
    for (int off = 1; off < 256; off <<= 1) {
        const int val = sp[t];
        const int add = (t >= off) ? sp[t - off] : 0;
        __syncthreads();
        sp[t] = val + add;
        __syncthreads();
    }
    int run = coff[c] + sp[t] - s;          // exclusive prefix for elem g0
#pragma unroll
    for (int i = 0; i < 4; ++i) {
        const int g = g0 + i;
        if (g < NNODE) {
            base[g]   = run;
            cursor[g] = run;
            run += v[i];
        } else if (g == NNODE) {
            base[g] = run;                  // == E
        }
    }
}

__global__ void gcur_init_kernel(const int* __restrict__ base,
                                 int* __restrict__ gcur) {
    if (threadIdx.x < 8) gcur[threadIdx.x] = base[GROWS * (int)threadIdx.x];
}

// Pass A: block-aggregated append into 8 coarse-group segments.
// One global atomicAdd per (block, group); each block writes 8 dense runs ->
// full cache lines, merged writebacks regardless of XCD placement.
__global__ __launch_bounds__(256) void append_kernel(
    const int* __restrict__ erow, const int* __restrict__ ecol,
    const float* __restrict__ eval, int* __restrict__ gcur,
    int* __restrict__ grow, int2* __restrict__ gpair, int E) {
    __shared__ int lcnt[8];
    __shared__ int lbase[8];
    const int t = threadIdx.x;
    if (t < 8) lcnt[t] = 0;
    __syncthreads();
    const int e0 = blockIdx.x * APB + t;
    int r[4], c[4], gr[4], rk[4];
    float v[4];
#pragma unroll
    for (int i = 0; i < 4; ++i) {
        const int e = e0 + 256 * i;
        if (e < E) {
            r[i] = erow[e];
            c[i] = ecol[e];
            v[i] = eval[e];
            gr[i] = (r[i] * 8) / NNODE;     // const div -> magic mul
            rk[i] = atomicAdd(&lcnt[gr[i]], 1);
        } else {
            gr[i] = -1;
        }
    }
    __syncthreads();
    if (t < 8 && lcnt[t] > 0) lbase[t] = atomicAdd(&gcur[t], lcnt[t]);
    __syncthreads();
#pragma unroll
    for (int i = 0; i < 4; ++i) {
        if (gr[i] >= 0) {
            const int pos = lbase[gr[i]] + rk[i];
            grow[pos]  = r[i];
            gpair[pos] = make_int2(c[i], __float_as_int(v[i]));
        }
    }
}

// Pass B: per-group CSR scatter. Source contiguous 3MB/group, dest 2MB slice;
// blockIdx&7 keeps a group's blocks on one XCD (perf heuristic only).
__global__ __launch_bounds__(256) void scatter2_kernel(
    const int* __restrict__ grow, const int2* __restrict__ gpair,
    const int* __restrict__ base, int* __restrict__ cursor,
    int2* __restrict__ epair) {
    const int g    = blockIdx.x & 7;
    const int rank = blockIdx.x >> 3;       // 0..NS2-1
    const int lo = base[GROWS * g];
    const int hi = base[GROWS * (g + 1)];
    for (int i = lo + rank * 256 + (int)threadIdx.x; i < hi; i += NS2 * 256) {
        const int r = grow[i];
        const int pos = atomicAdd(&cursor[r], 1);
        epair[pos] = gpair[i];
    }
}

// ---- SpMM, gather form, scalarized edge stream, 8 gathers in flight --------
// Stores a1 = lx + f (self term folded) and a2 = lx2.

__global__ __launch_bounds__(256) void spmm_kernel(
    const float* __restrict__ ue, const float* __restrict__ ie,
    const int2* __restrict__ epair, const int* __restrict__ base,
    float* __restrict__ lx, float* __restrict__ lx2) {
    const int lane = threadIdx.x & 63;
    int wv = (int)((blockIdx.x * blockDim.x + threadIdx.x) >> 6);
    wv = __builtin_amdgcn_readfirstlane(wv);
    const int nw = (int)((gridDim.x * blockDim.x) >> 6);
    for (int r = wv; r < NNODE; r += nw) {
        const int jb = base[r];
        const int je = base[r + 1];
        float acc1 = 0.f, acc2 = 0.f;
        int j = jb;
        for (; j + 8 <= je; j += 8) {
            int2 p[8];
#pragma unroll
            for (int t = 0; t < 8; ++t) p[t] = epair[j + t];
            float f[8];
#pragma unroll
            for (int t = 0; t < 8; ++t) f[t] = feat_row(ue, ie, p[t].x)[lane];
#pragma unroll
            for (int t = 0; t < 8; ++t) {
                const float v = __int_as_float(p[t].y);
                acc1 = fmaf(v, f[t], acc1);
                acc2 = fmaf(v * f[t], f[t], acc2);
            }
        }
        for (; j + 4 <= je; j += 4) {
            int2 p[4];
#pragma unroll
            for (int t = 0; t < 4; ++t) p[t] = epair[j + t];
            float f[4];
#pragma unroll
            for (int t = 0; t < 4; ++t) f[t] = feat_row(ue, ie, p[t].x)[lane];
#pragma unroll
            for (int t = 0; t < 4; ++t) {
                const float v = __int_as_float(p[t].y);
                acc1 = fmaf(v, f[t], acc1);
                acc2 = fmaf(v * f[t], f[t], acc2);
            }
        }
        for (; j < je; ++j) {
            const int2 p = epair[j];
            const float f = feat_row(ue, ie, p.x)[lane];
            const float v = __int_as_float(p.y);
            acc1 = fmaf(v, f, acc1);
            acc2 = fmaf(v * f, f, acc2);
        }
        lx [(size_t)r * DD + lane] = acc1 + feat_row(ue, ie, r)[lane];
        lx2[(size_t)r * DD + lane] = acc2;
    }
}

// ---- Tiled transform: out[n] = act(xa[n]@Wa + xb[n]@Wb + bias) -------------
// (round-7 notes: K-split waves, LDS broadcast reads, ds_add partials)

template <bool LRELU>
__global__ __launch_bounds__(256) void xform_kernel(
    const float* __restrict__ xa, const float* __restrict__ xb,
    const float* __restrict__ Wa, const float* __restrict__ Wb,
    const float* __restrict__ bias1, const float* __restrict__ bias2,
    float* __restrict__ out, int count) {
    __shared__ float sXa[64 * DD];
    __shared__ float sXb[64 * DD];
    __shared__ float sP [64 * DD];
    const int t     = threadIdx.x;
    const int lane  = t & 63;
    const int w     = t >> 6;
    const int khalf = (w & 1) * 32;
    const int rhalf = (w >> 1) * 32;

    float wva[32], wvb[32];
#pragma unroll
    for (int k = 0; k < 32; ++k) {
        wva[k] = Wa[(khalf + k) * DD + lane];
        wvb[k] = Wb[(khalf + k) * DD + lane];
    }

    const int base = blockIdx.x * 64;
    const float4* xav = (const float4*)xa;
    const float4* xbv = (const float4*)xb;
    float4* sXav = (float4*)sXa;
    float4* sXbv = (float4*)sXb;
    float4* sPv  = (float4*)sP;
#pragma unroll
    for (int i = 0; i < 4; ++i) {
        const int f4  = t + 256 * i;
        const int row = f4 >> 4;
        const int c   = f4 & 15;
        const int g   = min(base + row, count - 1);
        sXav[f4] = xav[(size_t)g * 16 + c];
        sXbv[f4] = xbv[(size_t)g * 16 + c];
        sPv[f4]  = make_float4(0.f, 0.f, 0.f, 0.f);
    }
    __syncthreads();

#pragma unroll 2
    for (int r = 0; r < 32; ++r) {
        const int row = rhalf + r;
        const float* ra = &sXa[row * DD + khalf];
        const float* rb = &sXb[row * DD + khalf];
        float o0 = 0.f, o1 = 0.f, o2 = 0.f, o3 = 0.f;
#pragma unroll
        for (int q = 0; q < 8; ++q) {
            const float4 qa = *(const float4*)(ra + 4 * q);
            const float4 qb = *(const float4*)(rb + 4 * q);
            o0 = fmaf(qa.x, wva[4 * q + 0], o0);
            o1 = fmaf(qa.y, wva[4 * q + 1], o1);
            o0 = fmaf(qa.z, wva[4 * q + 2], o0);
            o1 = fmaf(qa.w, wva[4 * q + 3], o1);
            o2 = fmaf(qb.x, wvb[4 * q + 0], o2);
            o3 = fmaf(qb.y, wvb[4 * q + 1], o3);
            o2 = fmaf(qb.z, wvb[4 * q + 2], o2);
            o3 = fmaf(qb.w, wvb[4 * q + 3], o3);
        }
        atomicAdd(&sP[row * DD + lane], (o0 + o1) + (o2 + o3));
    }
    __syncthreads();

    float4* outv = (float4*)out;
#pragma unroll
    for (int i = 0; i < 4; ++i) {
        const int f4  = t + 256 * i;
        const int row = f4 >> 4;
        const int c   = f4 & 15;
        const int g   = base + row;
        float4 v = sPv[f4];
        if (bias1) {
            const float4 b = ((const float4*)bias1)[c];
            v.x += b.x; v.y += b.y; v.z += b.z; v.w += b.w;
        }
        if (bias2) {
            const float4 b = ((const float4*)bias2)[c];
            v.x += b.x; v.y += b.y; v.z += b.z; v.w += b.w;
        }
        if (LRELU) {
            v.x = (v.x > 0.f) ? v.x : 0.01f * v.x;
            v.y = (v.y > 0.f) ? v.y : 0.01f * v.y;
            v.z = (v.z > 0.f) ? v.z : 0.01f * v.z;
            v.w = (v.w > 0.f) ? v.w : 0.01f * v.w;
        }
        if (g < count) outv[(size_t)g * 16 + c] = v;
    }
}

// ---- Per-sample MLP: o1 = relu(part_u + part_i); layers 2,3 ----------------

__global__ __launch_bounds__(256) void mlp_kernel(
    const float* __restrict__ part,
    const float* __restrict__ W2, const float* __restrict__ b2,
    const float* __restrict__ W3, const float* __restrict__ b3,
    const int* __restrict__ uid, const int* __restrict__ iid,
    float* __restrict__ out, int B) {
    __shared__ float sW2[DD * 32];
    __shared__ float sW3[32];
    for (int i = threadIdx.x; i < DD * 32; i += 256) sW2[i] = W2[i];
    if (threadIdx.x < 32) sW3[threadIdx.x] = W3[threadIdx.x];
    __syncthreads();
    const int lane = threadIdx.x & 63;
    const int wave = (int)((blockIdx.x * blockDim.x + threadIdx.x) >> 6);
    const int nw   = (int)((gridDim.x * blockDim.x) >> 6);
    const float bias2 = b2[lane & 31];
    const float w3v   = sW3[lane & 31];
    const float bias3 = b3[0];
    for (int s = wave; s < B; s += nw) {
        const int u  = uid[s];
        const int it = iid[s];
        const float pu = part[(size_t)u * DD + lane];
        const float pi = part[(size_t)(USER_NUM + it) * DD + lane];
        const float x  = pu + pi;
        const float o1 = (x > 0.f) ? x : 0.f;
        float acc_a = bias2, acc_b = 0.f;
#pragma unroll
        for (int k = 0; k < DD; k += 2) {
            acc_a = fmaf(__shfl(o1, k),     sW2[k * 32 + (lane & 31)],       acc_a);
            acc_b = fmaf(__shfl(o1, k + 1), sW2[(k + 1) * 32 + (lane & 31)], acc_b);
        }
        const float a2 = acc_a + acc_b;
        const float o2 = (a2 > 0.f) ? a2 : 0.f;
        float p = o2 * w3v;
        p += __shfl_xor(p, 1);
        p += __shfl_xor(p, 2);
        p += __shfl_xor(p, 4);
        p += __shfl_xor(p, 8);
        p += __shfl_xor(p, 16);
        if (lane == 0) out[s] = p + bias3;
    }
}

extern "C" void kernel_launch(void* const* d_in, const int* in_sizes, int n_in,
                              void* d_out, int out_size, void* d_ws, size_t ws_size,
                              hipStream_t stream) {
    const float* ue   = (const float*)d_in[0];
    const float* ie   = (const float*)d_in[1];
    const int*   erow = (const int*)d_in[2];
    const int*   ecol = (const int*)d_in[3];
    const float* evalp= (const float*)d_in[4];
    const float* Wg1  = (const float*)d_in[5];
    const float* bg1  = (const float*)d_in[6];
    const float* Wg2  = (const float*)d_in[7];
    const float* bg2  = (const float*)d_in[8];
    const float* W1   = (const float*)d_in[9];
    const float* b1   = (const float*)d_in[10];
    const float* W2   = (const float*)d_in[11];
    const float* b2   = (const float*)d_in[12];
    const float* W3   = (const float*)d_in[13];
    const float* b3   = (const float*)d_in[14];
    const int*   uid  = (const int*)d_in[15];
    const int*   iid  = (const int*)d_in[16];
    float* out = (float*)d_out;

    const int E = in_sizes[2];
    const int B = in_sizes[15];

    // workspace (~53.8 MB peak, unchanged):
    //   [lx 17.92MB][lx2 17.92MB][epair 16MB][cnt][cursor][base][csum][coff][gcur]
    // gpair(16MB) lives in lx region, grow(8MB) in lx2 region during CSR build
    // (both dead once spmm writes lx/lx2).
    // h (17.92MB) OVERLAYS [epair..] after spmm; part reuses lx2 after gcn.
    char* ws = (char*)d_ws;
    const size_t nd = (size_t)NNODE * DD;
    float* lx    = (float*)ws;
    float* lx2   = lx + nd;
    float* part  = lx2;                                     // alias (lx2 dead)
    int2*  gpair = (int2*)ws;                               // overlays lx
    int*   grow  = (int*)(ws + nd * sizeof(float));         // overlays lx2
    char*  tail  = ws + 2 * nd * sizeof(float);
    int2*  epair = (int2*)tail;
    int*   cnt   = (int*)(tail + (size_t)E * sizeof(int2));
    int*   cursor= cnt + NNODE;
    int*   base  = cursor + NNODE;                          // NNODE+1 ints
    int*   csum  = base + NNODE + 1;                        // NCHUNK ints
    int*   coff  = csum + NCHUNK;                           // NCHUNK ints
    int*   gcur  = coff + NCHUNK;                           // 8 ints
    float* h     = (float*)tail;                            // overlays epair..

    hipMemsetAsync(cnt, 0, NNODE * sizeof(int), stream);

    hist_kernel<<<2048, 256, 0, stream>>>(erow, cnt, E);
    chunksum_kernel<<<NCHUNK, 256, 0, stream>>>(cnt, csum);
    scan_small_kernel<<<1, 128, 0, stream>>>(csum, coff);
    fill_kernel<<<NCHUNK, 256, 0, stream>>>(cnt, coff, base, cursor);
    gcur_init_kernel<<<1, 8, 0, stream>>>(base, gcur);
    append_kernel<<<(E + APB - 1) / APB, 256, 0, stream>>>(
        erow, ecol, evalp, gcur, grow, gpair, E);
    scatter2_kernel<<<8 * NS2, 256, 0, stream>>>(grow, gpair, base, cursor, epair);
    spmm_kernel<<<4096, 256, 0, stream>>>(ue, ie, epair, base, lx, lx2);

    // h = leaky_relu(a1@Wg1 + a2@Wg2 + bg1 + bg2)
    xform_kernel<true><<<(NNODE + 63) / 64, 256, 0, stream>>>(
        lx, lx2, Wg1, Wg2, bg1, bg2, h, NNODE);
    // part (layer-1 partial): users then items
    xform_kernel<false><<<(USER_NUM + 63) / 64, 256, 0, stream>>>(
        ue, h, W1, W1 + DD * DD, b1, nullptr, part, USER_NUM);
    xform_kernel<false><<<(ITEM_NUM + 63) / 64, 256, 0, stream>>>(
        ie, h + (size_t)USER_NUM * DD, W1 + 2 * DD * DD, W1 + 3 * DD * DD,
        nullptr, nullptr, part + (size_t)USER_NUM * DD, ITEM_NUM);

    mlp_kernel<<<1024, 256, 0, stream>>>(part, W2, b2, W3, b3, uid, iid, out, B);
}

// Round 11
// 262.673 us; speedup vs baseline: 1.8332x; 1.8332x over previous
//
#include <hip/hip_runtime.h>
#include <hip/hip_bf16.h>

#define USER_NUM 50000
#define ITEM_NUM 20000
#define NNODE    70000
#define DD       64
#define CHUNK    1024
#define NCHUNK   ((NNODE + CHUNK - 1) / CHUNK)   // 69
#define GROWS    (NNODE / 8)                     // 8750 rows per coarse group
#define APB      1024                            // append: edges per block
#define NS2      128                             // scatter2: stripes per group

__device__ __forceinline__ const float* feat_row(const float* __restrict__ ue,
                                                 const float* __restrict__ ie, int n) {
    return (n < USER_NUM) ? (ue + (size_t)n * DD)
                          : (ie + (size_t)(n - USER_NUM) * DD);
}

// ---- Touched-node marking --------------------------------------------------

__global__ __launch_bounds__(256) void mark_kernel(const int* __restrict__ uid,
                                                   const int* __restrict__ iid,
                                                   int* __restrict__ tmask, int B) {
    const int stride = gridDim.x * blockDim.x;
    for (int s = blockIdx.x * blockDim.x + threadIdx.x; s < B; s += stride) {
        tmask[uid[s]] = 1;                       // racing same-value stores: benign
        tmask[USER_NUM + iid[s]] = 1;
    }
}

// ---- Generic 3-phase scan pieces -------------------------------------------

// Phase 1: per-chunk sums (coalesced strided loads + wave/block reduce).
__global__ __launch_bounds__(256) void chunksum_kernel(const int* __restrict__ arr,
                                                       int* __restrict__ csum) {
    __shared__ int red[4];
    const int c = blockIdx.x;
    const int t = threadIdx.x;
    int s = 0;
#pragma unroll
    for (int i = 0; i < 4; ++i) {
        const int idx = c * CHUNK + t + 256 * i;
        s += (idx < NNODE) ? arr[idx] : 0;
    }
#pragma unroll
    for (int off = 32; off; off >>= 1) s += __shfl_down(s, off);
    if ((t & 63) == 0) red[t >> 6] = s;
    __syncthreads();
    if (t == 0) csum[c] = red[0] + red[1] + red[2] + red[3];
}

// Phase 2: exclusive scan of the 69 chunk sums (one tiny block).
__global__ __launch_bounds__(128) void scan_small_kernel(const int* __restrict__ csum,
                                                         int* __restrict__ coff) {
    __shared__ int s[128];
    const int t = threadIdx.x;
    const int v = (t < NCHUNK) ? csum[t] : 0;
    s[t] = v;
    __syncthreads();
    for (int off = 1; off < 128; off <<= 1) {
        const int val = s[t];
        const int add = (t >= off) ? s[t - off] : 0;
        __syncthreads();
        s[t] = val + add;
        __syncthreads();
    }
    if (t < NCHUNK) coff[t] = s[t] - v;
}

// Phase 3a (flags): write cmap (full prefix), cmapx (slot or -1), nodes list,
// meta[0]=T (prefix at NNODE), meta[1]=Tu (prefix at USER_NUM).
__global__ __launch_bounds__(256) void fill_flags_kernel(
    const int* __restrict__ tmask, const int* __restrict__ coff,
    int* __restrict__ cmap, int* __restrict__ cmapx,
    int* __restrict__ nodes, int* __restrict__ meta) {
    __shared__ int sp[256];
    const int c  = blockIdx.x;
    const int t  = threadIdx.x;
    const int g0 = c * CHUNK + t * 4;
    int v[4];
#pragma unroll
    for (int i = 0; i < 4; ++i) v[i] = (g0 + i < NNODE) ? tmask[g0 + i] : 0;
    const int s = ((v[0] + v[1]) + (v[2] + v[3]));
    sp[t] = s;
    __syncthreads();
    for (int off = 1; off < 256; off <<= 1) {
        const int val = sp[t];
        const int add = (t >= off) ? sp[t - off] : 0;
        __syncthreads();
        sp[t] = val + add;
        __syncthreads();
    }
    int run = coff[c] + sp[t] - s;
#pragma unroll
    for (int i = 0; i < 4; ++i) {
        const int g = g0 + i;
        if (g < NNODE) {
            cmap[g]  = run;
            cmapx[g] = v[i] ? run : -1;
            if (v[i]) nodes[run] = g;
            if (g == USER_NUM) meta[1] = run;
            run += v[i];
        } else if (g == NNODE) {
            cmap[g] = run;
            meta[0] = run;
        }
    }
}

// Phase 3b (edge counts): write base AND cursor (compact CSR offsets).
__global__ __launch_bounds__(256) void fill_kernel(const int* __restrict__ cnt,
                                                   const int* __restrict__ coff,
                                                   int* __restrict__ base,
                                                   int* __restrict__ cursor) {
    __shared__ int sp[256];
    const int c  = blockIdx.x;
    const int t  = threadIdx.x;
    const int g0 = c * CHUNK + t * 4;
    int v[4];
#pragma unroll
    for (int i = 0; i < 4; ++i) v[i] = (g0 + i < NNODE) ? cnt[g0 + i] : 0;
    const int s = ((v[0] + v[1]) + (v[2] + v[3]));
    sp[t] = s;
    __syncthreads();
    for (int off = 1; off < 256; off <<= 1) {
        const int val = sp[t];
        const int add = (t >= off) ? sp[t - off] : 0;
        __syncthreads();
        sp[t] = val + add;
        __syncthreads();
    }
    int run = coff[c] + sp[t] - s;
#pragma unroll
    for (int i = 0; i < 4; ++i) {
        const int g = g0 + i;
        if (g < NNODE) {
            base[g]   = run;
            cursor[g] = run;
            run += v[i];
        } else if (g == NNODE) {
            base[g] = run;                  // == touched-edge count
        }
    }
}

// ---- Edge histogram over touched rows only ---------------------------------

__global__ __launch_bounds__(256) void hist2_kernel(const int* __restrict__ erow,
                                                    const int* __restrict__ cmapx,
                                                    int* __restrict__ cnt2, int E) {
    const int stride = gridDim.x * blockDim.x;
    for (int e = blockIdx.x * blockDim.x + threadIdx.x; e < E; e += stride) {
        const int slot = cmapx[erow[e]];
        if (slot >= 0) atomicAdd(&cnt2[slot], 1);
    }
}

__global__ void gcur_init_kernel(const int* __restrict__ cmap,
                                 const int* __restrict__ base2,
                                 int* __restrict__ gcur) {
    if (threadIdx.x < 8) gcur[threadIdx.x] = base2[cmap[GROWS * (int)threadIdx.x]];
}

// Pass A: block-aggregated append of TOUCHED edges into 8 node-range groups.
// One global atomicAdd per (block, group); dense full-line writes.
__global__ __launch_bounds__(256) void append_kernel(
    const int* __restrict__ erow, const int* __restrict__ ecol,
    const float* __restrict__ eval, const int* __restrict__ cmapx,
    int* __restrict__ gcur, int* __restrict__ grow, int2* __restrict__ gpair,
    int E) {
    __shared__ int lcnt[8];
    __shared__ int lbase[8];
    const int t = threadIdx.x;
    if (t < 8) lcnt[t] = 0;
    __syncthreads();
    const int e0 = blockIdx.x * APB + t;
    int sl[4], c[4], gr[4], rk[4];
    float v[4];
#pragma unroll
    for (int i = 0; i < 4; ++i) {
        const int e = e0 + 256 * i;
        gr[i] = -1;
        if (e < E) {
            const int r = erow[e];
            const int slot = cmapx[r];
            if (slot >= 0) {
                sl[i] = slot;
                c[i]  = ecol[e];
                v[i]  = eval[e];
                gr[i] = (r * 8) / NNODE;    // const div -> magic mul
                rk[i] = atomicAdd(&lcnt[gr[i]], 1);
            }
        }
    }
    __syncthreads();
    if (t < 8 && lcnt[t] > 0) lbase[t] = atomicAdd(&gcur[t], lcnt[t]);
    __syncthreads();
#pragma unroll
    for (int i = 0; i < 4; ++i) {
        if (gr[i] >= 0) {
            const int pos = lbase[gr[i]] + rk[i];
            grow[pos]  = sl[i];             // compact slot
            gpair[pos] = make_int2(c[i], __float_as_int(v[i]));
        }
    }
}

// Pass B: per-group CSR scatter (source contiguous, dest = group's slice).
__global__ __launch_bounds__(256) void scatter2_kernel(
    const int* __restrict__ grow, const int2* __restrict__ gpair,
    const int* __restrict__ cmap, const int* __restrict__ base2,
    int* __restrict__ cursor2, int2* __restrict__ epair) {
    const int g    = blockIdx.x & 7;
    const int rank = blockIdx.x >> 3;       // 0..NS2-1
    const int lo = base2[cmap[GROWS * g]];
    const int hi = base2[cmap[GROWS * (g + 1)]];
    for (int i = lo + rank * 256 + (int)threadIdx.x; i < hi; i += NS2 * 256) {
        const int slot = grow[i];
        const int pos = atomicAdd(&cursor2[slot], 1);
        epair[pos] = gpair[i];
    }
}

// ---- SpMM over compact touched rows ----------------------------------------
// Stores a1 = lx + f (self term folded) and a2 = lx2, compact-indexed.

__global__ __launch_bounds__(256) void spmm_kernel(
    const float* __restrict__ ue, const float* __restrict__ ie,
    const int2* __restrict__ epair, const int* __restrict__ base2,
    const int* __restrict__ nodes, const int* __restrict__ meta,
    float* __restrict__ lx, float* __restrict__ lx2) {
    const int T = meta[0];
    const int lane = threadIdx.x & 63;
    int wv = (int)((blockIdx.x * blockDim.x + threadIdx.x) >> 6);
    wv = __builtin_amdgcn_readfirstlane(wv);
    const int nw = (int)((gridDim.x * blockDim.x) >> 6);
    for (int r = wv; r < T; r += nw) {
        const int jb = base2[r];
        const int je = base2[r + 1];
        float acc1 = 0.f, acc2 = 0.f;
        int j = jb;
        for (; j + 8 <= je; j += 8) {
            int2 p[8];
#pragma unroll
            for (int t = 0; t < 8; ++t) p[t] = epair[j + t];
            float f[8];
#pragma unroll
            for (int t = 0; t < 8; ++t) f[t] = feat_row(ue, ie, p[t].x)[lane];
#pragma unroll
            for (int t = 0; t < 8; ++t) {
                const float v = __int_as_float(p[t].y);
                acc1 = fmaf(v, f[t], acc1);
                acc2 = fmaf(v * f[t], f[t], acc2);
            }
        }
        for (; j + 4 <= je; j += 4) {
            int2 p[4];
#pragma unroll
            for (int t = 0; t < 4; ++t) p[t] = epair[j + t];
            float f[4];
#pragma unroll
            for (int t = 0; t < 4; ++t) f[t] = feat_row(ue, ie, p[t].x)[lane];
#pragma unroll
            for (int t = 0; t < 4; ++t) {
                const float v = __int_as_float(p[t].y);
                acc1 = fmaf(v, f[t], acc1);
                acc2 = fmaf(v * f[t], f[t], acc2);
            }
        }
        for (; j < je; ++j) {
            const int2 p = epair[j];
            const float f = feat_row(ue, ie, p.x)[lane];
            const float v = __int_as_float(p.y);
            acc1 = fmaf(v, f, acc1);
            acc2 = fmaf(v * f, f, acc2);
        }
        const int n = nodes[r];
        lx [(size_t)r * DD + lane] = acc1 + feat_row(ue, ie, n)[lane];
        lx2[(size_t)r * DD + lane] = acc2;
    }
}

// ---- Tiled transform over compact slots ------------------------------------
// MODE 0: h = lrelu(lx@Wa + lx2@Wb + b1 + b2), slots [0,T)      (xa direct)
// MODE 1: part = f@Wa + h@Wb + b1,             slots [0,Tu)     (xa via nodes)
// MODE 2: part = f@Wa + h@Wb,                  slots [Tu,T)     (xa via nodes-USER)

template <int MODE>
__global__ __launch_bounds__(256) void xform_kernel(
    const float* __restrict__ xa, const float* __restrict__ xb,
    const float* __restrict__ Wa, const float* __restrict__ Wb,
    const float* __restrict__ bias1, const float* __restrict__ bias2,
    float* __restrict__ out,
    const int* __restrict__ nodes, const int* __restrict__ meta) {
    int start, lim;
    if (MODE == 0)      { start = 0;       lim = meta[0]; }
    else if (MODE == 1) { start = 0;       lim = meta[1]; }
    else                { start = meta[1]; lim = meta[0]; }
    const int tb = start + (int)blockIdx.x * 64;
    if (tb >= lim) return;

    __shared__ float sXa[64 * DD];
    __shared__ float sXb[64 * DD];
    __shared__ float sP [64 * DD];
    const int t     = threadIdx.x;
    const int lane  = t & 63;
    const int w     = t >> 6;
    const int khalf = (w & 1) * 32;
    const int rhalf = (w >> 1) * 32;

    float wva[32], wvb[32];
#pragma unroll
    for (int k = 0; k < 32; ++k) {
        wva[k] = Wa[(khalf + k) * DD + lane];
        wvb[k] = Wb[(khalf + k) * DD + lane];
    }

    float4* sXav = (float4*)sXa;
    float4* sXbv = (float4*)sXb;
    float4* sPv  = (float4*)sP;
#pragma unroll
    for (int i = 0; i < 4; ++i) {
        const int f4  = t + 256 * i;
        const int row = f4 >> 4;
        const int c   = f4 & 15;
        const int g   = min(tb + row, lim - 1);
        const float* xar;
        if (MODE == 0) {
            xar = xa + (size_t)g * DD;
        } else {
            int n = nodes[g];
            if (MODE == 2) n -= USER_NUM;
            xar = xa + (size_t)n * DD;
        }
        sXav[f4] = ((const float4*)xar)[c];
        sXbv[f4] = ((const float4*)(xb + (size_t)g * DD))[c];
        sPv[f4]  = make_float4(0.f, 0.f, 0.f, 0.f);
    }
    __syncthreads();

#pragma unroll 2
    for (int r = 0; r < 32; ++r) {
        const int row = rhalf + r;
        const float* ra = &sXa[row * DD + khalf];
        const float* rb = &sXb[row * DD + khalf];
        float o0 = 0.f, o1 = 0.f, o2 = 0.f, o3 = 0.f;
#pragma unroll
        for (int q = 0; q < 8; ++q) {
            const float4 qa = *(const float4*)(ra + 4 * q);
            const float4 qb = *(const float4*)(rb + 4 * q);
            o0 = fmaf(qa.x, wva[4 * q + 0], o0);
            o1 = fmaf(qa.y, wva[4 * q + 1], o1);
            o0 = fmaf(qa.z, wva[4 * q + 2], o0);
            o1 = fmaf(qa.w, wva[4 * q + 3], o1);
            o2 = fmaf(qb.x, wvb[4 * q + 0], o2);
            o3 = fmaf(qb.y, wvb[4 * q + 1], o3);
            o2 = fmaf(qb.z, wvb[4 * q + 2], o2);
            o3 = fmaf(qb.w, wvb[4 * q + 3], o3);
        }
        atomicAdd(&sP[row * DD + lane], (o0 + o1) + (o2 + o3));
    }
    __syncthreads();

    float4* outv = (float4*)out;
#pragma unroll
    for (int i = 0; i < 4; ++i) {
        const int f4  = t + 256 * i;
        const int row = f4 >> 4;
        const int c   = f4 & 15;
        const int g   = tb + row;
        float4 v = sPv[f4];
        if (bias1) {
            const float4 b = ((const float4*)bias1)[c];
            v.x += b.x; v.y += b.y; v.z += b.z; v.w += b.w;
        }
        if (bias2) {
            const float4 b = ((const float4*)bias2)[c];
            v.x += b.x; v.y += b.y; v.z += b.z; v.w += b.w;
        }
        if (MODE == 0) {
            v.x = (v.x > 0.f) ? v.x : 0.01f * v.x;
            v.y = (v.y > 0.f) ? v.y : 0.01f * v.y;
            v.z = (v.z > 0.f) ? v.z : 0.01f * v.z;
            v.w = (v.w > 0.f) ? v.w : 0.01f * v.w;
        }
        if (g < lim) outv[(size_t)g * 16 + c] = v;
    }
}

// ---- Per-sample MLP: o1 = relu(part_u + part_i); layers 2,3 ----------------

__global__ __launch_bounds__(256) void mlp_kernel(
    const float* __restrict__ part, const int* __restrict__ cmapx,
    const float* __restrict__ W2, const float* __restrict__ b2,
    const float* __restrict__ W3, const float* __restrict__ b3,
    const int* __restrict__ uid, const int* __restrict__ iid,
    float* __restrict__ out, int B) {
    __shared__ float sW2[DD * 32];
    __shared__ float sW3[32];
    for (int i = threadIdx.x; i < DD * 32; i += 256) sW2[i] = W2[i];
    if (threadIdx.x < 32) sW3[threadIdx.x] = W3[threadIdx.x];
    __syncthreads();
    const int lane = threadIdx.x & 63;
    const int wave = (int)((blockIdx.x * blockDim.x + threadIdx.x) >> 6);
    const int nw   = (int)((gridDim.x * blockDim.x) >> 6);
    const float bias2 = b2[lane & 31];
    const float w3v   = sW3[lane & 31];
    const float bias3 = b3[0];
    for (int s = wave; s < B; s += nw) {
        const int su = cmapx[uid[s]];
        const int si = cmapx[USER_NUM + iid[s]];
        const float pu = part[(size_t)su * DD + lane];
        const float pi = part[(size_t)si * DD + lane];
        const float x  = pu + pi;
        const float o1 = (x > 0.f) ? x : 0.f;
        float acc_a = bias2, acc_b = 0.f;
#pragma unroll
        for (int k = 0; k < DD; k += 2) {
            acc_a = fmaf(__shfl(o1, k),     sW2[k * 32 + (lane & 31)],       acc_a);
            acc_b = fmaf(__shfl(o1, k + 1), sW2[(k + 1) * 32 + (lane & 31)], acc_b);
        }
        const float a2 = acc_a + acc_b;
        const float o2 = (a2 > 0.f) ? a2 : 0.f;
        float p = o2 * w3v;
        p += __shfl_xor(p, 1);
        p += __shfl_xor(p, 2);
        p += __shfl_xor(p, 4);
        p += __shfl_xor(p, 8);
        p += __shfl_xor(p, 16);
        if (lane == 0) out[s] = p + bias3;
    }
}

extern "C" void kernel_launch(void* const* d_in, const int* in_sizes, int n_in,
                              void* d_out, int out_size, void* d_ws, size_t ws_size,
                              hipStream_t stream) {
    const float* ue   = (const float*)d_in[0];
    const float* ie   = (const float*)d_in[1];
    const int*   erow = (const int*)d_in[2];
    const int*   ecol = (const int*)d_in[3];
    const float* evalp= (const float*)d_in[4];
    const float* Wg1  = (const float*)d_in[5];
    const float* bg1  = (const float*)d_in[6];
    const float* Wg2  = (const float*)d_in[7];
    const float* bg2  = (const float*)d_in[8];
    const float* W1   = (const float*)d_in[9];
    const float* b1   = (const float*)d_in[10];
    const float* W2   = (const float*)d_in[11];
    const float* b2   = (const float*)d_in[12];
    const float* W3   = (const float*)d_in[13];
    const float* b3   = (const float*)d_in[14];
    const int*   uid  = (const int*)d_in[15];
    const int*   iid  = (const int*)d_in[16];
    float* out = (float*)d_out;

    const int E = in_sizes[2];
    const int B = in_sizes[15];

    // Compact-domain bounds (host-side grid caps; exact T/Tu live in meta[]).
    const int TU_MAX = (B < USER_NUM) ? B : USER_NUM;   // touched users <= B
    const int TI_MAX = (B < ITEM_NUM) ? B : ITEM_NUM;   // touched items <= B
    const int T_MAX  = TU_MAX + TI_MAX;                 // 32768 here

    // workspace (~53.5 MB):
    //  [lx 17.92MB][lx2 17.92MB][epair 16MB][cnt2|tmask|cursor2|base2|cmap|
    //   cmapx|nodes|csum|coff|gcur|meta  ~1.7MB]
    // gpair overlays lx, grow overlays lx2 (dead before spmm writes them).
    // h overlays epair (T_MAX*256B = 8.4MB < 16MB); part overlays lx2.
    char* ws = (char*)d_ws;
    const size_t nd = (size_t)NNODE * DD;
    float* lx    = (float*)ws;
    float* lx2   = lx + nd;
    float* part  = lx2;                                 // alias (lx2 dead)
    int2*  gpair = (int2*)ws;                           // overlays lx
    int*   grow  = (int*)(ws + nd * sizeof(float));     // overlays lx2
    char*  tail  = ws + 2 * nd * sizeof(float);
    int2*  epair = (int2*)tail;
    float* h     = (float*)tail;                        // overlays epair after spmm
    int*   cnt2  = (int*)(tail + (size_t)E * sizeof(int2));
    int*   tmask = cnt2 + NNODE;                        // zeroed with cnt2
    int*   cursor2 = tmask + NNODE;
    int*   base2 = cursor2 + NNODE;                     // NNODE+1
    int*   cmap  = base2 + NNODE + 1;                   // NNODE+1 (full prefix)
    int*   cmapx = cmap + NNODE + 1;                    // NNODE (slot or -1)
    int*   nodes = cmapx + NNODE;                       // NNODE (slot -> node)
    int*   csum  = nodes + NNODE;                       // NCHUNK
    int*   coff  = csum + NCHUNK;                       // NCHUNK
    int*   gcur  = coff + NCHUNK;                       // 8
    int*   meta  = gcur + 8;                            // [0]=T, [1]=Tu

    hipMemsetAsync(cnt2, 0, 2 * NNODE * sizeof(int), stream);   // cnt2 + tmask

    mark_kernel<<<(B + 255) / 256, 256, 0, stream>>>(uid, iid, tmask, B);
    chunksum_kernel<<<NCHUNK, 256, 0, stream>>>(tmask, csum);
    scan_small_kernel<<<1, 128, 0, stream>>>(csum, coff);
    fill_flags_kernel<<<NCHUNK, 256, 0, stream>>>(tmask, coff, cmap, cmapx,
                                                  nodes, meta);
    hist2_kernel<<<2048, 256, 0, stream>>>(erow, cmapx, cnt2, E);
    chunksum_kernel<<<NCHUNK, 256, 0, stream>>>(cnt2, csum);
    scan_small_kernel<<<1, 128, 0, stream>>>(csum, coff);
    fill_kernel<<<NCHUNK, 256, 0, stream>>>(cnt2, coff, base2, cursor2);
    gcur_init_kernel<<<1, 8, 0, stream>>>(cmap, base2, gcur);
    append_kernel<<<(E + APB - 1) / APB, 256, 0, stream>>>(
        erow, ecol, evalp, cmapx, gcur, grow, gpair, E);
    scatter2_kernel<<<8 * NS2, 256, 0, stream>>>(grow, gpair, cmap, base2,
                                                 cursor2, epair);
    spmm_kernel<<<4096, 256, 0, stream>>>(ue, ie, epair, base2, nodes, meta,
                                          lx, lx2);

    // h = lrelu(lx@Wg1 + lx2@Wg2 + bg1 + bg2) over compact slots
    xform_kernel<0><<<(T_MAX + 63) / 64, 256, 0, stream>>>(
        lx, lx2, Wg1, Wg2, bg1, bg2, h, nodes, meta);
    // part = f@W1a + h@W1b (+b1 for users), compact slots
    xform_kernel<1><<<(TU_MAX + 63) / 64, 256, 0, stream>>>(
        ue, h, W1, W1 + DD * DD, b1, nullptr, part, nodes, meta);
    xform_kernel<2><<<(TI_MAX + 63) / 64, 256, 0, stream>>>(
        ie, h, W1 + 2 * DD * DD, W1 + 3 * DD * DD, nullptr, nullptr, part,
        nodes, meta);

    mlp_kernel<<<1024, 256, 0, stream>>>(part, cmapx, W2, b2, W3, b3,
                                         uid, iid, out, B);
}

// Round 12
// 253.444 us; speedup vs baseline: 1.9000x; 1.0364x over previous
//
#include <hip/hip_runtime.h>
#include <hip/hip_bf16.h>

#define USER_NUM 50000
#define ITEM_NUM 20000
#define NNODE    70000
#define DD       64
#define CHUNK    1024
#define NCHUNK   ((NNODE + CHUNK - 1) / CHUNK)   // 69
#define GROWS    (NNODE / 8)                     // 8750 rows per coarse group
#define APB      1024                            // append: edges per block
#define NS2      128                             // hist3/scatter2 stripes/group
#define T_CAP    32768                           // max touched slots (B=16384)
#define NCHUNK2  (T_CAP / CHUNK)                 // 32
#define GCAP     327680                          // per-group edge capacity

__device__ __forceinline__ const float* feat_row(const float* __restrict__ ue,
                                                 const float* __restrict__ ie, int n) {
    return (n < USER_NUM) ? (ue + (size_t)n * DD)
                          : (ie + (size_t)(n - USER_NUM) * DD);
}

// ---- init: zero cnt2/tmask, seed gcur --------------------------------------

__global__ __launch_bounds__(256) void zero_kernel(int* __restrict__ cnt2,
                                                   int* __restrict__ tmask,
                                                   int* __restrict__ gcur) {
    const int tid    = blockIdx.x * 256 + (int)threadIdx.x;
    const int stride = gridDim.x * 256;
    for (int i = tid; i < T_CAP; i += stride) cnt2[i] = 0;
    for (int i = tid; i < NNODE; i += stride) tmask[i] = 0;
    if (tid < 8) gcur[tid] = tid * GCAP;
}

// ---- Touched-node marking --------------------------------------------------

__global__ __launch_bounds__(256) void mark_kernel(const int* __restrict__ uid,
                                                   const int* __restrict__ iid,
                                                   int* __restrict__ tmask, int B) {
    const int stride = gridDim.x * blockDim.x;
    for (int s = blockIdx.x * blockDim.x + threadIdx.x; s < B; s += stride) {
        tmask[uid[s]] = 1;                       // racing same-value stores: benign
        tmask[USER_NUM + iid[s]] = 1;
    }
}

// ---- Generic 3-phase scan pieces (domain size N as arg) --------------------

__global__ __launch_bounds__(256) void chunksum_kernel(const int* __restrict__ arr,
                                                       int* __restrict__ csum, int N) {
    __shared__ int red[4];
    const int c = blockIdx.x;
    const int t = threadIdx.x;
    int s = 0;
#pragma unroll
    for (int i = 0; i < 4; ++i) {
        const int idx = c * CHUNK + t + 256 * i;
        s += (idx < N) ? arr[idx] : 0;
    }
#pragma unroll
    for (int off = 32; off; off >>= 1) s += __shfl_down(s, off);
    if ((t & 63) == 0) red[t >> 6] = s;
    __syncthreads();
    if (t == 0) csum[c] = red[0] + red[1] + red[2] + red[3];
}

__global__ __launch_bounds__(128) void scan_small_kernel(const int* __restrict__ csum,
                                                         int* __restrict__ coff,
                                                         int NC) {
    __shared__ int s[128];
    const int t = threadIdx.x;
    const int v = (t < NC) ? csum[t] : 0;
    s[t] = v;
    __syncthreads();
    for (int off = 1; off < 128; off <<= 1) {
        const int val = s[t];
        const int add = (t >= off) ? s[t - off] : 0;
        __syncthreads();
        s[t] = val + add;
        __syncthreads();
    }
    if (t < NC) coff[t] = s[t] - v;
}

// Flags fill (NNODE domain): cmapx (slot or -1), nodes, meta[0]=T, meta[1]=Tu.
__global__ __launch_bounds__(256) void fill_flags_kernel(
    const int* __restrict__ tmask, const int* __restrict__ coff,
    int* __restrict__ cmapx, int* __restrict__ nodes, int* __restrict__ meta) {
    __shared__ int sp[256];
    const int c  = blockIdx.x;
    const int t  = threadIdx.x;
    const int g0 = c * CHUNK + t * 4;
    int v[4];
#pragma unroll
    for (int i = 0; i < 4; ++i) v[i] = (g0 + i < NNODE) ? tmask[g0 + i] : 0;
    const int s = ((v[0] + v[1]) + (v[2] + v[3]));
    sp[t] = s;
    __syncthreads();
    for (int off = 1; off < 256; off <<= 1) {
        const int val = sp[t];
        const int add = (t >= off) ? sp[t - off] : 0;
        __syncthreads();
        sp[t] = val + add;
        __syncthreads();
    }
    int run = coff[c] + sp[t] - s;
#pragma unroll
    for (int i = 0; i < 4; ++i) {
        const int g = g0 + i;
        if (g < NNODE) {
            cmapx[g] = v[i] ? run : -1;
            if (v[i]) nodes[run] = g;
            if (g == USER_NUM) meta[1] = run;
            run += v[i];
        } else if (g == NNODE) {
            meta[0] = run;
        }
    }
    if (g0 + 4 == NNODE) meta[0] = run;     // safety if NNODE aligns to 4*t
}

// Counts fill (N-domain, N multiple of 4): base + cursor; base[N]=total.
__global__ __launch_bounds__(256) void fill_kernel(const int* __restrict__ cnt,
                                                   const int* __restrict__ coff,
                                                   int* __restrict__ base,
                                                   int* __restrict__ cursor, int N) {
    __shared__ int sp[256];
    const int c  = blockIdx.x;
    const int t  = threadIdx.x;
    const int g0 = c * CHUNK + t * 4;
    int v[4];
#pragma unroll
    for (int i = 0; i < 4; ++i) v[i] = (g0 + i < N) ? cnt[g0 + i] : 0;
    const int s = ((v[0] + v[1]) + (v[2] + v[3]));
    sp[t] = s;
    __syncthreads();
    for (int off = 1; off < 256; off <<= 1) {
        const int val = sp[t];
        const int add = (t >= off) ? sp[t - off] : 0;
        __syncthreads();
        sp[t] = val + add;
        __syncthreads();
    }
    int run = coff[c] + sp[t] - s;
#pragma unroll
    for (int i = 0; i < 4; ++i) {
        const int g = g0 + i;
        if (g < N) {
            base[g]   = run;
            cursor[g] = run;
            run += v[i];
        }
    }
    if (g0 + 4 == N) base[N] = run;
}

// ---- Pass A: block-aggregated append of TOUCHED edges into 8 segments ------
// Segment g starts at g*GCAP. One global atomicAdd per (block, group);
// dense full-line writes.

__global__ __launch_bounds__(256) void append_kernel(
    const int* __restrict__ erow, const int* __restrict__ ecol,
    const float* __restrict__ eval, const int* __restrict__ cmapx,
    int* __restrict__ gcur, int* __restrict__ grow, int2* __restrict__ gpair,
    int E) {
    __shared__ int lcnt[8];
    __shared__ int lbase[8];
    const int t = threadIdx.x;
    if (t < 8) lcnt[t] = 0;
    __syncthreads();
    const int e0 = blockIdx.x * APB + t;
    int sl[4], c[4], gr[4], rk[4];
    float v[4];
#pragma unroll
    for (int i = 0; i < 4; ++i) {
        const int e = e0 + 256 * i;
        gr[i] = -1;
        if (e < E) {
            const int r = erow[e];
            const int slot = cmapx[r];
            if (slot >= 0) {
                sl[i] = slot;
                c[i]  = ecol[e];
                v[i]  = eval[e];
                gr[i] = (r * 8) / NNODE;    // const div -> magic mul
                rk[i] = atomicAdd(&lcnt[gr[i]], 1);
            }
        }
    }
    __syncthreads();
    if (t < 8 && lcnt[t] > 0) lbase[t] = atomicAdd(&gcur[t], lcnt[t]);
    __syncthreads();
#pragma unroll
    for (int i = 0; i < 4; ++i) {
        if (gr[i] >= 0) {
            const int pos = lbase[gr[i]] + rk[i];
            grow[pos]  = sl[i];             // compact slot
            gpair[pos] = make_int2(c[i], __float_as_int(v[i]));
        }
    }
}

// ---- Histogram over compacted slot stream (sequential reads) ---------------

__global__ __launch_bounds__(256) void hist3_kernel(const int* __restrict__ grow,
                                                    const int* __restrict__ gcur,
                                                    int* __restrict__ cnt2) {
    const int g    = blockIdx.x & 7;
    const int rank = blockIdx.x >> 3;       // 0..NS2-1
    const int hi = gcur[g];
    for (int i = g * GCAP + rank * 256 + (int)threadIdx.x; i < hi; i += NS2 * 256)
        atomicAdd(&cnt2[grow[i]], 1);
}

// ---- Pass B: per-group CSR scatter ------------------------------------------

__global__ __launch_bounds__(256) void scatter2_kernel(
    const int* __restrict__ grow, const int2* __restrict__ gpair,
    const int* __restrict__ gcur, int* __restrict__ cursor2,
    int2* __restrict__ epair) {
    const int g    = blockIdx.x & 7;
    const int rank = blockIdx.x >> 3;       // 0..NS2-1
    const int hi = gcur[g];
    for (int i = g * GCAP + rank * 256 + (int)threadIdx.x; i < hi; i += NS2 * 256) {
        const int slot = grow[i];
        const int pos = atomicAdd(&cursor2[slot], 1);
        epair[pos] = gpair[i];
    }
}

// ---- SpMM over compact touched rows ----------------------------------------
// Stores a1 = lx + f (self term folded) and a2 = lx2, compact-indexed.

__global__ __launch_bounds__(256) void spmm_kernel(
    const float* __restrict__ ue, const float* __restrict__ ie,
    const int2* __restrict__ epair, const int* __restrict__ base2,
    const int* __restrict__ nodes, const int* __restrict__ meta,
    float* __restrict__ lx, float* __restrict__ lx2) {
    const int T = meta[0];
    const int lane = threadIdx.x & 63;
    int wv = (int)((blockIdx.x * blockDim.x + threadIdx.x) >> 6);
    wv = __builtin_amdgcn_readfirstlane(wv);
    const int nw = (int)((gridDim.x * blockDim.x) >> 6);
    for (int r = wv; r < T; r += nw) {
        const int jb = base2[r];
        const int je = base2[r + 1];
        float acc1 = 0.f, acc2 = 0.f;
        int j = jb;
        for (; j + 8 <= je; j += 8) {
            int2 p[8];
#pragma unroll
            for (int t = 0; t < 8; ++t) p[t] = epair[j + t];
            float f[8];
#pragma unroll
            for (int t = 0; t < 8; ++t) f[t] = feat_row(ue, ie, p[t].x)[lane];
#pragma unroll
            for (int t = 0; t < 8; ++t) {
                const float v = __int_as_float(p[t].y);
                acc1 = fmaf(v, f[t], acc1);
                acc2 = fmaf(v * f[t], f[t], acc2);
            }
        }
        for (; j + 4 <= je; j += 4) {
            int2 p[4];
#pragma unroll
            for (int t = 0; t < 4; ++t) p[t] = epair[j + t];
            float f[4];
#pragma unroll
            for (int t = 0; t < 4; ++t) f[t] = feat_row(ue, ie, p[t].x)[lane];
#pragma unroll
            for (int t = 0; t < 4; ++t) {
                const float v = __int_as_float(p[t].y);
                acc1 = fmaf(v, f[t], acc1);
                acc2 = fmaf(v * f[t], f[t], acc2);
            }
        }
        for (; j < je; ++j) {
            const int2 p = epair[j];
            const float f = feat_row(ue, ie, p.x)[lane];
            const float v = __int_as_float(p.y);
            acc1 = fmaf(v, f, acc1);
            acc2 = fmaf(v * f, f, acc2);
        }
        const int n = nodes[r];
        lx [(size_t)r * DD + lane] = acc1 + feat_row(ue, ie, n)[lane];
        lx2[(size_t)r * DD + lane] = acc2;
    }
}

// ---- Tiled transform over compact slots ------------------------------------
// MODE 0: h = lrelu(lx@Wa + lx2@Wb + b1 + b2), slots [0,T)      (xa direct)
// MODE 1: part = f@Wa + h@Wb + b1,             slots [0,Tu)     (xa via nodes)
// MODE 2: part = f@Wa + h@Wb,                  slots [Tu,T)     (xa via nodes-USER)

template <int MODE>
__global__ __launch_bounds__(256) void xform_kernel(
    const float* __restrict__ xa, const float* __restrict__ xb,
    const float* __restrict__ Wa, const float* __restrict__ Wb,
    const float* __restrict__ bias1, const float* __restrict__ bias2,
    float* __restrict__ out,
    const int* __restrict__ nodes, const int* __restrict__ meta) {
    int start, lim;
    if (MODE == 0)      { start = 0;       lim = meta[0]; }
    else if (MODE == 1) { start = 0;       lim = meta[1]; }
    else                { start = meta[1]; lim = meta[0]; }
    const int tb = start + (int)blockIdx.x * 64;
    if (tb >= lim) return;

    __shared__ float sXa[64 * DD];
    __shared__ float sXb[64 * DD];
    __shared__ float sP [64 * DD];
    const int t     = threadIdx.x;
    const int lane  = t & 63;
    const int w     = t >> 6;
    const int khalf = (w & 1) * 32;
    const int rhalf = (w >> 1) * 32;

    float wva[32], wvb[32];
#pragma unroll
    for (int k = 0; k < 32; ++k) {
        wva[k] = Wa[(khalf + k) * DD + lane];
        wvb[k] = Wb[(khalf + k) * DD + lane];
    }

    float4* sXav = (float4*)sXa;
    float4* sXbv = (float4*)sXb;
    float4* sPv  = (float4*)sP;
#pragma unroll
    for (int i = 0; i < 4; ++i) {
        const int f4  = t + 256 * i;
        const int row = f4 >> 4;
        const int c   = f4 & 15;
        const int g   = min(tb + row, lim - 1);
        const float* xar;
        if (MODE == 0) {
            xar = xa + (size_t)g * DD;
        } else {
            int n = nodes[g];
            if (MODE == 2) n -= USER_NUM;
            xar = xa + (size_t)n * DD;
        }
        sXav[f4] = ((const float4*)xar)[c];
        sXbv[f4] = ((const float4*)(xb + (size_t)g * DD))[c];
        sPv[f4]  = make_float4(0.f, 0.f, 0.f, 0.f);
    }
    __syncthreads();

#pragma unroll 2
    for (int r = 0; r < 32; ++r) {
        const int row = rhalf + r;
        const float* ra = &sXa[row * DD + khalf];
        const float* rb = &sXb[row * DD + khalf];
        float o0 = 0.f, o1 = 0.f, o2 = 0.f, o3 = 0.f;
#pragma unroll
        for (int q = 0; q < 8; ++q) {
            const float4 qa = *(const float4*)(ra + 4 * q);
            const float4 qb = *(const float4*)(rb + 4 * q);
            o0 = fmaf(qa.x, wva[4 * q + 0], o0);
            o1 = fmaf(qa.y, wva[4 * q + 1], o1);
            o0 = fmaf(qa.z, wva[4 * q + 2], o0);
            o1 = fmaf(qa.w, wva[4 * q + 3], o1);
            o2 = fmaf(qb.x, wvb[4 * q + 0], o2);
            o3 = fmaf(qb.y, wvb[4 * q + 1], o3);
            o2 = fmaf(qb.z, wvb[4 * q + 2], o2);
            o3 = fmaf(qb.w, wvb[4 * q + 3], o3);
        }
        atomicAdd(&sP[row * DD + lane], (o0 + o1) + (o2 + o3));
    }
    __syncthreads();

    float4* outv = (float4*)out;
#pragma unroll
    for (int i = 0; i < 4; ++i) {
        const int f4  = t + 256 * i;
        const int row = f4 >> 4;
        const int c   = f4 & 15;
        const int g   = tb + row;
        float4 v = sPv[f4];
        if (bias1) {
            const float4 b = ((const float4*)bias1)[c];
            v.x += b.x; v.y += b.y; v.z += b.z; v.w += b.w;
        }
        if (bias2) {
            const float4 b = ((const float4*)bias2)[c];
            v.x += b.x; v.y += b.y; v.z += b.z; v.w += b.w;
        }
        if (MODE == 0) {
            v.x = (v.x > 0.f) ? v.x : 0.01f * v.x;
            v.y = (v.y > 0.f) ? v.y : 0.01f * v.y;
            v.z = (v.z > 0.f) ? v.z : 0.01f * v.z;
            v.w = (v.w > 0.f) ? v.w : 0.01f * v.w;
        }
        if (g < lim) outv[(size_t)g * 16 + c] = v;
    }
}

// ---- Per-sample MLP: o1 = relu(part_u + part_i); layers 2,3 ----------------

__global__ __launch_bounds__(256) void mlp_kernel(
    const float* __restrict__ part, const int* __restrict__ cmapx,
    const float* __restrict__ W2, const float* __restrict__ b2,
    const float* __restrict__ W3, const float* __restrict__ b3,
    const int* __restrict__ uid, const int* __restrict__ iid,
    float* __restrict__ out, int B) {
    __shared__ float sW2[DD * 32];
    __shared__ float sW3[32];
    for (int i = threadIdx.x; i < DD * 32; i += 256) sW2[i] = W2[i];
    if (threadIdx.x < 32) sW3[threadIdx.x] = W3[threadIdx.x];
    __syncthreads();
    const int lane = threadIdx.x & 63;
    const int wave = (int)((blockIdx.x * blockDim.x + threadIdx.x) >> 6);
    const int nw   = (int)((gridDim.x * blockDim.x) >> 6);
    const float bias2 = b2[lane & 31];
    const float w3v   = sW3[lane & 31];
    const float bias3 = b3[0];
    for (int s = wave; s < B; s += nw) {
        const int su = cmapx[uid[s]];
        const int si = cmapx[USER_NUM + iid[s]];
        const float pu = part[(size_t)su * DD + lane];
        const float pi = part[(size_t)si * DD + lane];
        const float x  = pu + pi;
        const float o1 = (x > 0.f) ? x : 0.f;
        float acc_a = bias2, acc_b = 0.f;
#pragma unroll
        for (int k = 0; k < DD; k += 2) {
            acc_a = fmaf(__shfl(o1, k),     sW2[k * 32 + (lane & 31)],       acc_a);
            acc_b = fmaf(__shfl(o1, k + 1), sW2[(k + 1) * 32 + (lane & 31)], acc_b);
        }
        const float a2 = acc_a + acc_b;
        const float o2 = (a2 > 0.f) ? a2 : 0.f;
        float p = o2 * w3v;
        p += __shfl_xor(p, 1);
        p += __shfl_xor(p, 2);
        p += __shfl_xor(p, 4);
        p += __shfl_xor(p, 8);
        p += __shfl_xor(p, 16);
        if (lane == 0) out[s] = p + bias3;
    }
}

extern "C" void kernel_launch(void* const* d_in, const int* in_sizes, int n_in,
                              void* d_out, int out_size, void* d_ws, size_t ws_size,
                              hipStream_t stream) {
    const float* ue   = (const float*)d_in[0];
    const float* ie   = (const float*)d_in[1];
    const int*   erow = (const int*)d_in[2];
    const int*   ecol = (const int*)d_in[3];
    const float* evalp= (const float*)d_in[4];
    const float* Wg1  = (const float*)d_in[5];
    const float* bg1  = (const float*)d_in[6];
    const float* Wg2  = (const float*)d_in[7];
    const float* bg2  = (const float*)d_in[8];
    const float* W1   = (const float*)d_in[9];
    const float* b1   = (const float*)d_in[10];
    const float* W2   = (const float*)d_in[11];
    const float* b2   = (const float*)d_in[12];
    const float* W3   = (const float*)d_in[13];
    const float* b3   = (const float*)d_in[14];
    const int*   uid  = (const int*)d_in[15];
    const int*   iid  = (const int*)d_in[16];
    float* out = (float*)d_out;

    const int E = in_sizes[2];
    const int B = in_sizes[15];

    const int TU_MAX = (B < USER_NUM) ? B : USER_NUM;   // touched users <= B
    const int TI_MAX = (B < ITEM_NUM) ? B : ITEM_NUM;   // touched items <= B
    const int T_MAX  = TU_MAX + TI_MAX;                 // <= T_CAP (32768)

    // workspace layout (~49.5 MB peak):
    //  [A: 32MB  lx|lx2|h|part (8MB each, compact T_CAP rows)]
    //    - during CSR build, grow(8*GCAP*4=10.5MB)+gpair(8*GCAP*8=21MB)
    //      overlay region A (both dead before spmm writes lx/lx2)
    //  [B: epair 16MB]
    //  [C: misc ints ~1.4MB]
    char* ws = (char*)d_ws;
    const size_t ndc = (size_t)T_CAP * DD;              // 2,097,152 floats = 8MB
    float* lx    = (float*)ws;
    float* lx2   = lx + ndc;
    float* h     = lx2 + ndc;
    float* part  = h + ndc;
    int*   grow  = (int*)ws;                            // 8*GCAP ints (10.5MB)
    int2*  gpair = (int2*)(ws + 11u * 1024 * 1024);     // 8*GCAP int2 (21MB) ends 32MB
    char*  tail  = ws + 32u * 1024 * 1024;
    int2*  epair = (int2*)tail;                         // E int2 = 16MB
    int*   mi    = (int*)(tail + (size_t)E * sizeof(int2));
    int*   cnt2    = mi;                                // T_CAP
    int*   cursor2 = cnt2 + T_CAP;                      // T_CAP
    int*   base2   = cursor2 + T_CAP;                   // T_CAP+1
    int*   tmask   = base2 + T_CAP + 1;                 // NNODE
    int*   cmapx   = tmask + NNODE;                     // NNODE
    int*   nodes   = cmapx + NNODE;                     // T_CAP
    int*   csum    = nodes + T_CAP;                     // 128
    int*   coff    = csum + 128;                        // 128
    int*   gcur    = coff + 128;                        // 8
    int*   meta    = gcur + 8;                          // [0]=T, [1]=Tu

    zero_kernel<<<512, 256, 0, stream>>>(cnt2, tmask, gcur);
    mark_kernel<<<(B + 255) / 256, 256, 0, stream>>>(uid, iid, tmask, B);
    chunksum_kernel<<<NCHUNK, 256, 0, stream>>>(tmask, csum, NNODE);
    scan_small_kernel<<<1, 128, 0, stream>>>(csum, coff, NCHUNK);
    fill_flags_kernel<<<NCHUNK, 256, 0, stream>>>(tmask, coff, cmapx, nodes, meta);
    append_kernel<<<(E + APB - 1) / APB, 256, 0, stream>>>(
        erow, ecol, evalp, cmapx, gcur, grow, gpair, E);
    hist3_kernel<<<8 * NS2, 256, 0, stream>>>(grow, gcur, cnt2);
    chunksum_kernel<<<NCHUNK2, 256, 0, stream>>>(cnt2, csum, T_CAP);
    scan_small_kernel<<<1, 128, 0, stream>>>(csum, coff, NCHUNK2);
    fill_kernel<<<NCHUNK2, 256, 0, stream>>>(cnt2, coff, base2, cursor2, T_CAP);
    scatter2_kernel<<<8 * NS2, 256, 0, stream>>>(grow, gpair, gcur, cursor2, epair);
    spmm_kernel<<<4096, 256, 0, stream>>>(ue, ie, epair, base2, nodes, meta,
                                          lx, lx2);

    // h = lrelu(lx@Wg1 + lx2@Wg2 + bg1 + bg2) over compact slots
    xform_kernel<0><<<(T_MAX + 63) / 64, 256, 0, stream>>>(
        lx, lx2, Wg1, Wg2, bg1, bg2, h, nodes, meta);
    // part = f@W1a + h@W1b (+b1 for users), compact slots
    xform_kernel<1><<<(TU_MAX + 63) / 64, 256, 0, stream>>>(
        ue, h, W1, W1 + DD * DD, b1, nullptr, part, nodes, meta);
    xform_kernel<2><<<(TI_MAX + 63) / 64, 256, 0, stream>>>(
        ie, h, W1 + 2 * DD * DD, W1 + 3 * DD * DD, nullptr, nullptr, part,
        nodes, meta);

    mlp_kernel<<<1024, 256, 0, stream>>>(part, cmapx, W2, b2, W3, b3,
                                         uid, iid, out, B);
}

// Round 13
// 246.654 us; speedup vs baseline: 1.9523x; 1.0275x over previous
//
#include <hip/hip_runtime.h>
#include <hip/hip_bf16.h>

#define USER_NUM 50000
#define ITEM_NUM 20000
#define NNODE    70000
#define DD       64
#define CHUNK    1024
#define NCHUNK   ((NNODE + CHUNK - 1) / CHUNK)   // 69
#define APB      1024                            // append: edges per block
#define NS2      128                             // scatter2 stripes per group
#define T_CAP    32768                           // max touched slots (B=16384)
#define NCHUNK2  (T_CAP / CHUNK)                 // 32
#define GCAP     327680                          // per-group edge capacity

__device__ __forceinline__ const float* feat_row(const float* __restrict__ ue,
                                                 const float* __restrict__ ie, int n) {
    return (n < USER_NUM) ? (ue + (size_t)n * DD)
                          : (ie + (size_t)(n - USER_NUM) * DD);
}

// ---- init: zero cnt2/tmask, seed gcur --------------------------------------

__global__ __launch_bounds__(256) void zero_kernel(int* __restrict__ cnt2,
                                                   int* __restrict__ tmask,
                                                   int* __restrict__ gcur) {
    const int tid    = blockIdx.x * 256 + (int)threadIdx.x;
    const int stride = gridDim.x * 256;
    for (int i = tid; i < T_CAP; i += stride) cnt2[i] = 0;
    for (int i = tid; i < NNODE; i += stride) tmask[i] = 0;
    if (tid < 8) gcur[tid] = tid * GCAP;
}

// ---- Touched-node marking --------------------------------------------------

__global__ __launch_bounds__(256) void mark_kernel(const int* __restrict__ uid,
                                                   const int* __restrict__ iid,
                                                   int* __restrict__ tmask, int B) {
    const int stride = gridDim.x * blockDim.x;
    for (int s = blockIdx.x * blockDim.x + threadIdx.x; s < B; s += stride) {
        tmask[uid[s]] = 1;                       // racing same-value stores: benign
        tmask[USER_NUM + iid[s]] = 1;
    }
}

// ---- Generic 3-phase scan pieces (domain size N as arg) --------------------

__global__ __launch_bounds__(256) void chunksum_kernel(const int* __restrict__ arr,
                                                       int* __restrict__ csum, int N) {
    __shared__ int red[4];
    const int c = blockIdx.x;
    const int t = threadIdx.x;
    int s = 0;
#pragma unroll
    for (int i = 0; i < 4; ++i) {
        const int idx = c * CHUNK + t + 256 * i;
        s += (idx < N) ? arr[idx] : 0;
    }
#pragma unroll
    for (int off = 32; off; off >>= 1) s += __shfl_down(s, off);
    if ((t & 63) == 0) red[t >> 6] = s;
    __syncthreads();
    if (t == 0) csum[c] = red[0] + red[1] + red[2] + red[3];
}

__global__ __launch_bounds__(128) void scan_small_kernel(const int* __restrict__ csum,
                                                         int* __restrict__ coff,
                                                         int NC) {
    __shared__ int s[128];
    const int t = threadIdx.x;
    const int v = (t < NC) ? csum[t] : 0;
    s[t] = v;
    __syncthreads();
    for (int off = 1; off < 128; off <<= 1) {
        const int val = s[t];
        const int add = (t >= off) ? s[t - off] : 0;
        __syncthreads();
        s[t] = val + add;
        __syncthreads();
    }
    if (t < NC) coff[t] = s[t] - v;
}

// Flags fill (NNODE domain): cmapx (slot or -1), nodes, meta[0]=T, meta[1]=Tu.
__global__ __launch_bounds__(256) void fill_flags_kernel(
    const int* __restrict__ tmask, const int* __restrict__ coff,
    int* __restrict__ cmapx, int* __restrict__ nodes, int* __restrict__ meta) {
    __shared__ int sp[256];
    const int c  = blockIdx.x;
    const int t  = threadIdx.x;
    const int g0 = c * CHUNK + t * 4;
    int v[4];
#pragma unroll
    for (int i = 0; i < 4; ++i) v[i] = (g0 + i < NNODE) ? tmask[g0 + i] : 0;
    const int s = ((v[0] + v[1]) + (v[2] + v[3]));
    sp[t] = s;
    __syncthreads();
    for (int off = 1; off < 256; off <<= 1) {
        const int val = sp[t];
        const int add = (t >= off) ? sp[t - off] : 0;
        __syncthreads();
        sp[t] = val + add;
        __syncthreads();
    }
    int run = coff[c] + sp[t] - s;
#pragma unroll
    for (int i = 0; i < 4; ++i) {
        const int g = g0 + i;
        if (g < NNODE) {
            cmapx[g] = v[i] ? run : -1;
            if (v[i]) nodes[run] = g;
            if (g == USER_NUM) meta[1] = run;
            run += v[i];
        } else if (g == NNODE) {
            meta[0] = run;
        }
    }
    if (g0 + 4 == NNODE) meta[0] = run;     // safety if NNODE aligns to 4*t
}

// Counts fill (N-domain, N multiple of 4): base + cursor; base[N]=total.
__global__ __launch_bounds__(256) void fill_kernel(const int* __restrict__ cnt,
                                                   const int* __restrict__ coff,
                                                   int* __restrict__ base,
                                                   int* __restrict__ cursor, int N) {
    __shared__ int sp[256];
    const int c  = blockIdx.x;
    const int t  = threadIdx.x;
    const int g0 = c * CHUNK + t * 4;
    int v[4];
#pragma unroll
    for (int i = 0; i < 4; ++i) v[i] = (g0 + i < N) ? cnt[g0 + i] : 0;
    const int s = ((v[0] + v[1]) + (v[2] + v[3]));
    sp[t] = s;
    __syncthreads();
    for (int off = 1; off < 256; off <<= 1) {
        const int val = sp[t];
        const int add = (t >= off) ? sp[t - off] : 0;
        __syncthreads();
        sp[t] = val + add;
        __syncthreads();
    }
    int run = coff[c] + sp[t] - s;
#pragma unroll
    for (int i = 0; i < 4; ++i) {
        const int g = g0 + i;
        if (g < N) {
            base[g]   = run;
            cursor[g] = run;
            run += v[i];
        }
    }
    if (g0 + 4 == N) base[N] = run;
}

// ---- Pass A: block-aggregated append of TOUCHED edges + fused histogram ----
// Segment g starts at g*GCAP. One global atomicAdd per (block, group) for the
// segment cursor; per-edge atomicAdd on cnt2 builds the CSR histogram in the
// same pass (saves a later re-scan of grow).

__global__ __launch_bounds__(256) void append_kernel(
    const int* __restrict__ erow, const int* __restrict__ ecol,
    const float* __restrict__ eval, const int* __restrict__ cmapx,
    int* __restrict__ gcur, int* __restrict__ grow, int2* __restrict__ gpair,
    int* __restrict__ cnt2, int E) {
    __shared__ int lcnt[8];
    __shared__ int lbase[8];
    const int t = threadIdx.x;
    if (t < 8) lcnt[t] = 0;
    __syncthreads();
    const int e0 = blockIdx.x * APB + t;
    int sl[4], c[4], gr[4], rk[4];
    float v[4];
#pragma unroll
    for (int i = 0; i < 4; ++i) {
        const int e = e0 + 256 * i;
        gr[i] = -1;
        if (e < E) {
            const int r = erow[e];
            const int slot = cmapx[r];
            if (slot >= 0) {
                sl[i] = slot;
                c[i]  = ecol[e];
                v[i]  = eval[e];
                gr[i] = (r * 8) / NNODE;    // const div -> magic mul
                rk[i] = atomicAdd(&lcnt[gr[i]], 1);
            }
        }
    }
    __syncthreads();
    if (t < 8 && lcnt[t] > 0) lbase[t] = atomicAdd(&gcur[t], lcnt[t]);
    __syncthreads();
#pragma unroll
    for (int i = 0; i < 4; ++i) {
        if (gr[i] >= 0) {
            const int pos = lbase[gr[i]] + rk[i];
            grow[pos]  = sl[i];             // compact slot
            gpair[pos] = make_int2(c[i], __float_as_int(v[i]));
            atomicAdd(&cnt2[sl[i]], 1);     // fused histogram
        }
    }
}

// ---- Pass B: per-group CSR scatter ------------------------------------------

__global__ __launch_bounds__(256) void scatter2_kernel(
    const int* __restrict__ grow, const int2* __restrict__ gpair,
    const int* __restrict__ gcur, int* __restrict__ cursor2,
    int2* __restrict__ epair) {
    const int g    = blockIdx.x & 7;
    const int rank = blockIdx.x >> 3;       // 0..NS2-1
    const int hi = gcur[g];
    for (int i = g * GCAP + rank * 256 + (int)threadIdx.x; i < hi; i += NS2 * 256) {
        const int slot = grow[i];
        const int pos = atomicAdd(&cursor2[slot], 1);
        epair[pos] = gpair[i];
    }
}

// ---- SpMM over compact touched rows ----------------------------------------
// Stores a1 = lx + f (self term folded) and a2 = lx2, compact-indexed.

__global__ __launch_bounds__(256) void spmm_kernel(
    const float* __restrict__ ue, const float* __restrict__ ie,
    const int2* __restrict__ epair, const int* __restrict__ base2,
    const int* __restrict__ nodes, const int* __restrict__ meta,
    float* __restrict__ lx, float* __restrict__ lx2) {
    const int T = meta[0];
    const int lane = threadIdx.x & 63;
    int wv = (int)((blockIdx.x * blockDim.x + threadIdx.x) >> 6);
    wv = __builtin_amdgcn_readfirstlane(wv);
    const int nw = (int)((gridDim.x * blockDim.x) >> 6);
    for (int r = wv; r < T; r += nw) {
        const int jb = base2[r];
        const int je = base2[r + 1];
        float acc1 = 0.f, acc2 = 0.f;
        int j = jb;
        for (; j + 8 <= je; j += 8) {
            int2 p[8];
#pragma unroll
            for (int t = 0; t < 8; ++t) p[t] = epair[j + t];
            float f[8];
#pragma unroll
            for (int t = 0; t < 8; ++t) f[t] = feat_row(ue, ie, p[t].x)[lane];
#pragma unroll
            for (int t = 0; t < 8; ++t) {
                const float v = __int_as_float(p[t].y);
                acc1 = fmaf(v, f[t], acc1);
                acc2 = fmaf(v * f[t], f[t], acc2);
            }
        }
        for (; j + 4 <= je; j += 4) {
            int2 p[4];
#pragma unroll
            for (int t = 0; t < 4; ++t) p[t] = epair[j + t];
            float f[4];
#pragma unroll
            for (int t = 0; t < 4; ++t) f[t] = feat_row(ue, ie, p[t].x)[lane];
#pragma unroll
            for (int t = 0; t < 4; ++t) {
                const float v = __int_as_float(p[t].y);
                acc1 = fmaf(v, f[t], acc1);
                acc2 = fmaf(v * f[t], f[t], acc2);
            }
        }
        for (; j < je; ++j) {
            const int2 p = epair[j];
            const float f = feat_row(ue, ie, p.x)[lane];
            const float v = __int_as_float(p.y);
            acc1 = fmaf(v, f, acc1);
            acc2 = fmaf(v * f, f, acc2);
        }
        const int n = nodes[r];
        lx [(size_t)r * DD + lane] = acc1 + feat_row(ue, ie, n)[lane];
        lx2[(size_t)r * DD + lane] = acc2;
    }
}

// ---- Fused transform: GCN h (in LDS only) + MLP layer-1 partial ------------
// Per 64-slot tile:
//   phase1: h = lrelu(lx@Wg1 + lx2@Wg2 + bg1 + bg2)   -> kept in LDS
//   phase2: part = f@W1a + h@W1b (+ b1 for users)     -> global
// IS_USER=1 covers slots [0,Tu), IS_USER=0 covers [Tu,T). h never hits memory.
// Waves k-split as before (64 weight VGPRs each), partials via LDS atomics.

template <int IS_USER>
__global__ __launch_bounds__(256) void xform_fused_kernel(
    const float* __restrict__ lx, const float* __restrict__ lx2,
    const float* __restrict__ fb,       // ue (users) or ie (items)
    const float* __restrict__ Wg1, const float* __restrict__ Wg2,
    const float* __restrict__ bg1, const float* __restrict__ bg2,
    const float* __restrict__ W1, const float* __restrict__ b1,
    float* __restrict__ part,
    const int* __restrict__ nodes, const int* __restrict__ meta) {
    const int Tu = meta[1];
    const int T  = meta[0];
    const int start = IS_USER ? 0  : Tu;
    const int lim   = IS_USER ? Tu : T;
    const int tb = start + (int)blockIdx.x * 64;
    if (tb >= lim) return;

    __shared__ float sXa[64 * DD];      // phase1: lx      phase2: h
    __shared__ float sXb[64 * DD];      // phase1: lx2     phase2: f
    __shared__ float sP [64 * DD];
    const int t     = threadIdx.x;
    const int lane  = t & 63;
    const int w     = t >> 6;
    const int khalf = (w & 1) * 32;
    const int rhalf = (w >> 1) * 32;

    float wva[32], wvb[32];
#pragma unroll
    for (int k = 0; k < 32; ++k) {
        wva[k] = Wg1[(khalf + k) * DD + lane];
        wvb[k] = Wg2[(khalf + k) * DD + lane];
    }

    float4* sXav = (float4*)sXa;
    float4* sXbv = (float4*)sXb;
    float4* sPv  = (float4*)sP;
#pragma unroll
    for (int i = 0; i < 4; ++i) {
        const int f4  = t + 256 * i;
        const int row = f4 >> 4;
        const int c   = f4 & 15;
        const int g   = min(tb + row, lim - 1);
        sXav[f4] = ((const float4*)(lx  + (size_t)g * DD))[c];
        sXbv[f4] = ((const float4*)(lx2 + (size_t)g * DD))[c];
        sPv[f4]  = make_float4(0.f, 0.f, 0.f, 0.f);
    }
    __syncthreads();

    // phase 1: h partials
#pragma unroll 2
    for (int r = 0; r < 32; ++r) {
        const int row = rhalf + r;
        const float* ra = &sXa[row * DD + khalf];
        const float* rb = &sXb[row * DD + khalf];
        float o0 = 0.f, o1 = 0.f, o2 = 0.f, o3 = 0.f;
#pragma unroll
        for (int q = 0; q < 8; ++q) {
            const float4 qa = *(const float4*)(ra + 4 * q);
            const float4 qb = *(const float4*)(rb + 4 * q);
            o0 = fmaf(qa.x, wva[4 * q + 0], o0);
            o1 = fmaf(qa.y, wva[4 * q + 1], o1);
            o0 = fmaf(qa.z, wva[4 * q + 2], o0);
            o1 = fmaf(qa.w, wva[4 * q + 3], o1);
            o2 = fmaf(qb.x, wvb[4 * q + 0], o2);
            o3 = fmaf(qb.y, wvb[4 * q + 1], o3);
            o2 = fmaf(qb.z, wvb[4 * q + 2], o2);
            o3 = fmaf(qb.w, wvb[4 * q + 3], o3);
        }
        atomicAdd(&sP[row * DD + lane], (o0 + o1) + (o2 + o3));
    }
    __syncthreads();

    // epilogue 1: h = lrelu(sP + bg1 + bg2) -> sXa; reset sP; stage f -> sXb
#pragma unroll
    for (int i = 0; i < 4; ++i) {
        const int f4  = t + 256 * i;
        const int row = f4 >> 4;
        const int c   = f4 & 15;
        float4 v = sPv[f4];
        const float4 ba = ((const float4*)bg1)[c];
        const float4 bb = ((const float4*)bg2)[c];
        v.x += ba.x + bb.x; v.y += ba.y + bb.y;
        v.z += ba.z + bb.z; v.w += ba.w + bb.w;
        v.x = (v.x > 0.f) ? v.x : 0.01f * v.x;
        v.y = (v.y > 0.f) ? v.y : 0.01f * v.y;
        v.z = (v.z > 0.f) ? v.z : 0.01f * v.z;
        v.w = (v.w > 0.f) ? v.w : 0.01f * v.w;
        sXav[f4] = v;                        // h
        sPv[f4]  = make_float4(0.f, 0.f, 0.f, 0.f);
        const int g = min(tb + row, lim - 1);
        int n = nodes[g];
        if (!IS_USER) n -= USER_NUM;
        sXbv[f4] = ((const float4*)(fb + (size_t)n * DD))[c];   // f
    }

    // phase-2 weights: sXa(h) pairs W1b, sXb(f) pairs W1a
    const float* W1a = W1 + (IS_USER ? 0 : 2 * DD * DD);
    const float* W1b = W1a + DD * DD;
#pragma unroll
    for (int k = 0; k < 32; ++k) {
        wva[k] = W1b[(khalf + k) * DD + lane];
        wvb[k] = W1a[(khalf + k) * DD + lane];
    }
    __syncthreads();

    // phase 2: part partials
#pragma unroll 2
    for (int r = 0; r < 32; ++r) {
        const int row = rhalf + r;
        const float* ra = &sXa[row * DD + khalf];
        const float* rb = &sXb[row * DD + khalf];
        float o0 = 0.f, o1 = 0.f, o2 = 0.f, o3 = 0.f;
#pragma unroll
        for (int q = 0; q < 8; ++q) {
            const float4 qa = *(const float4*)(ra + 4 * q);
            const float4 qb = *(const float4*)(rb + 4 * q);
            o0 = fmaf(qa.x, wva[4 * q + 0], o0);
            o1 = fmaf(qa.y, wva[4 * q + 1], o1);
            o0 = fmaf(qa.z, wva[4 * q + 2], o0);
            o1 = fmaf(qa.w, wva[4 * q + 3], o1);
            o2 = fmaf(qb.x, wvb[4 * q + 0], o2);
            o3 = fmaf(qb.y, wvb[4 * q + 1], o3);
            o2 = fmaf(qb.z, wvb[4 * q + 2], o2);
            o3 = fmaf(qb.w, wvb[4 * q + 3], o3);
        }
        atomicAdd(&sP[row * DD + lane], (o0 + o1) + (o2 + o3));
    }
    __syncthreads();

    // epilogue 2: part = sP (+ b1 for users)
    float4* outv = (float4*)part;
#pragma unroll
    for (int i = 0; i < 4; ++i) {
        const int f4  = t + 256 * i;
        const int row = f4 >> 4;
        const int c   = f4 & 15;
        const int g   = tb + row;
        float4 v = sPv[f4];
        if (IS_USER) {
            const float4 b = ((const float4*)b1)[c];
            v.x += b.x; v.y += b.y; v.z += b.z; v.w += b.w;
        }
        if (g < lim) outv[(size_t)g * 16 + c] = v;
    }
}

// ---- Per-sample MLP: o1 = relu(part_u + part_i); layers 2,3 ----------------

__global__ __launch_bounds__(256) void mlp_kernel(
    const float* __restrict__ part, const int* __restrict__ cmapx,
    const float* __restrict__ W2, const float* __restrict__ b2,
    const float* __restrict__ W3, const float* __restrict__ b3,
    const int* __restrict__ uid, const int* __restrict__ iid,
    float* __restrict__ out, int B) {
    __shared__ float sW2[DD * 32];
    __shared__ float sW3[32];
    for (int i = threadIdx.x; i < DD * 32; i += 256) sW2[i] = W2[i];
    if (threadIdx.x < 32) sW3[threadIdx.x] = W3[threadIdx.x];
    __syncthreads();
    const int lane = threadIdx.x & 63;
    const int wave = (int)((blockIdx.x * blockDim.x + threadIdx.x) >> 6);
    const int nw   = (int)((gridDim.x * blockDim.x) >> 6);
    const float bias2 = b2[lane & 31];
    const float w3v   = sW3[lane & 31];
    const float bias3 = b3[0];
    for (int s = wave; s < B; s += nw) {
        const int su = cmapx[uid[s]];
        const int si = cmapx[USER_NUM + iid[s]];
        const float pu = part[(size_t)su * DD + lane];
        const float pi = part[(size_t)si * DD + lane];
        const float x  = pu + pi;
        const float o1 = (x > 0.f) ? x : 0.f;
        float acc_a = bias2, acc_b = 0.f;
#pragma unroll
        for (int k = 0; k < DD; k += 2) {
            acc_a = fmaf(__shfl(o1, k),     sW2[k * 32 + (lane & 31)],       acc_a);
            acc_b = fmaf(__shfl(o1, k + 1), sW2[(k + 1) * 32 + (lane & 31)], acc_b);
        }
        const float a2 = acc_a + acc_b;
        const float o2 = (a2 > 0.f) ? a2 : 0.f;
        float p = o2 * w3v;
        p += __shfl_xor(p, 1);
        p += __shfl_xor(p, 2);
        p += __shfl_xor(p, 4);
        p += __shfl_xor(p, 8);
        p += __shfl_xor(p, 16);
        if (lane == 0) out[s] = p + bias3;
    }
}

extern "C" void kernel_launch(void* const* d_in, const int* in_sizes, int n_in,
                              void* d_out, int out_size, void* d_ws, size_t ws_size,
                              hipStream_t stream) {
    const float* ue   = (const float*)d_in[0];
    const float* ie   = (const float*)d_in[1];
    const int*   erow = (const int*)d_in[2];
    const int*   ecol = (const int*)d_in[3];
    const float* evalp= (const float*)d_in[4];
    const float* Wg1  = (const float*)d_in[5];
    const float* bg1  = (const float*)d_in[6];
    const float* Wg2  = (const float*)d_in[7];
    const float* bg2  = (const float*)d_in[8];
    const float* W1   = (const float*)d_in[9];
    const float* b1   = (const float*)d_in[10];
    const float* W2   = (const float*)d_in[11];
    const float* b2   = (const float*)d_in[12];
    const float* W3   = (const float*)d_in[13];
    const float* b3   = (const float*)d_in[14];
    const int*   uid  = (const int*)d_in[15];
    const int*   iid  = (const int*)d_in[16];
    float* out = (float*)d_out;

    const int E = in_sizes[2];
    const int B = in_sizes[15];

    const int TU_MAX = (B < USER_NUM) ? B : USER_NUM;   // touched users <= B
    const int TI_MAX = (B < ITEM_NUM) ? B : ITEM_NUM;   // touched items <= B

    // workspace layout (~49.5 MB peak):
    //  [A: 32MB  lx|lx2|part (8MB each, compact T_CAP rows) + 8MB spare]
    //    - during CSR build, grow(10.5MB)+gpair(21MB) overlay region A
    //      (both dead before spmm writes lx/lx2)
    //  [B: epair 16MB]
    //  [C: misc ints ~1.2MB]
    char* ws = (char*)d_ws;
    const size_t ndc = (size_t)T_CAP * DD;              // 8MB per array
    float* lx    = (float*)ws;
    float* lx2   = lx + ndc;
    float* part  = lx2 + ndc;
    int*   grow  = (int*)ws;                            // 8*GCAP ints (10.5MB)
    int2*  gpair = (int2*)(ws + 11u * 1024 * 1024);     // 8*GCAP int2 (21MB)
    char*  tail  = ws + 32u * 1024 * 1024;
    int2*  epair = (int2*)tail;                         // E int2 = 16MB
    int*   mi    = (int*)(tail + (size_t)E * sizeof(int2));
    int*   cnt2    = mi;                                // T_CAP
    int*   cursor2 = cnt2 + T_CAP;                      // T_CAP
    int*   base2   = cursor2 + T_CAP;                   // T_CAP+1
    int*   tmask   = base2 + T_CAP + 1;                 // NNODE
    int*   cmapx   = tmask + NNODE;                     // NNODE
    int*   nodes   = cmapx + NNODE;                     // T_CAP
    int*   csum    = nodes + T_CAP;                     // 128
    int*   coff    = csum + 128;                        // 128
    int*   gcur    = coff + 128;                        // 8
    int*   meta    = gcur + 8;                          // [0]=T, [1]=Tu

    zero_kernel<<<512, 256, 0, stream>>>(cnt2, tmask, gcur);
    mark_kernel<<<(B + 255) / 256, 256, 0, stream>>>(uid, iid, tmask, B);
    chunksum_kernel<<<NCHUNK, 256, 0, stream>>>(tmask, csum, NNODE);
    scan_small_kernel<<<1, 128, 0, stream>>>(csum, coff, NCHUNK);
    fill_flags_kernel<<<NCHUNK, 256, 0, stream>>>(tmask, coff, cmapx, nodes, meta);
    append_kernel<<<(E + APB - 1) / APB, 256, 0, stream>>>(
        erow, ecol, evalp, cmapx, gcur, grow, gpair, cnt2, E);
    chunksum_kernel<<<NCHUNK2, 256, 0, stream>>>(cnt2, csum, T_CAP);
    scan_small_kernel<<<1, 128, 0, stream>>>(csum, coff, NCHUNK2);
    fill_kernel<<<NCHUNK2, 256, 0, stream>>>(cnt2, coff, base2, cursor2, T_CAP);
    scatter2_kernel<<<8 * NS2, 256, 0, stream>>>(grow, gpair, gcur, cursor2, epair);
    spmm_kernel<<<4096, 256, 0, stream>>>(ue, ie, epair, base2, nodes, meta,
                                          lx, lx2);

    // fused: h in LDS, part to global (users then items)
    xform_fused_kernel<1><<<(TU_MAX + 63) / 64, 256, 0, stream>>>(
        lx, lx2, ue, Wg1, Wg2, bg1, bg2, W1, b1, part, nodes, meta);
    xform_fused_kernel<0><<<(TI_MAX + 63) / 64, 256, 0, stream>>>(
        lx, lx2, ie, Wg1, Wg2, bg1, bg2, W1, b1, part, nodes, meta);

    mlp_kernel<<<1024, 256, 0, stream>>>(part, cmapx, W2, b2, W3, b3,
                                         uid, iid, out, B);
}

// Round 14
// 230.701 us; speedup vs baseline: 2.0873x; 1.0691x over previous
//
#include <hip/hip_runtime.h>
#include <hip/hip_bf16.h>

#define USER_NUM 50000
#define ITEM_NUM 20000
#define NNODE    70000
#define DD       64
#define CHUNK    1024
#define NCHUNK   ((NNODE + CHUNK - 1) / CHUNK)   // 69
#define GROWS    (NNODE / 8)                     // 8750 rows per coarse group
#define APB      2048                            // append: edges per block
#define EPT      8                               // append: edges per thread
#define NS2      128                             // scatter2 stripes per group
#define NB3      16                              // hist3 blocks per group
#define T_CAP    32768                           // max touched slots (B=16384)
#define NCHUNK2  (T_CAP / CHUNK)                 // 32
#define GCAP     327680                          // per-group edge capacity

__device__ __forceinline__ const float* feat_row(const float* __restrict__ ue,
                                                 const float* __restrict__ ie, int n) {
    return (n < USER_NUM) ? (ue + (size_t)n * DD)
                          : (ie + (size_t)(n - USER_NUM) * DD);
}

// ---- init: zero cnt2/tmask, seed gcur --------------------------------------

__global__ __launch_bounds__(256) void zero_kernel(int* __restrict__ cnt2,
                                                   int* __restrict__ tmask,
                                                   int* __restrict__ gcur) {
    const int tid    = blockIdx.x * 256 + (int)threadIdx.x;
    const int stride = gridDim.x * 256;
    for (int i = tid; i < T_CAP; i += stride) cnt2[i] = 0;
    for (int i = tid; i < NNODE; i += stride) tmask[i] = 0;
    if (tid < 8) gcur[tid] = tid * GCAP;
}

// ---- Touched-node marking --------------------------------------------------

__global__ __launch_bounds__(256) void mark_kernel(const int* __restrict__ uid,
                                                   const int* __restrict__ iid,
                                                   int* __restrict__ tmask, int B) {
    const int stride = gridDim.x * blockDim.x;
    for (int s = blockIdx.x * blockDim.x + threadIdx.x; s < B; s += stride) {
        tmask[uid[s]] = 1;                       // racing same-value stores: benign
        tmask[USER_NUM + iid[s]] = 1;
    }
}

// ---- Generic 3-phase scan pieces (domain size N as arg) --------------------

__global__ __launch_bounds__(256) void chunksum_kernel(const int* __restrict__ arr,
                                                       int* __restrict__ csum, int N) {
    __shared__ int red[4];
    const int c = blockIdx.x;
    const int t = threadIdx.x;
    int s = 0;
#pragma unroll
    for (int i = 0; i < 4; ++i) {
        const int idx = c * CHUNK + t + 256 * i;
        s += (idx < N) ? arr[idx] : 0;
    }
#pragma unroll
    for (int off = 32; off; off >>= 1) s += __shfl_down(s, off);
    if ((t & 63) == 0) red[t >> 6] = s;
    __syncthreads();
    if (t == 0) csum[c] = red[0] + red[1] + red[2] + red[3];
}

__global__ __launch_bounds__(128) void scan_small_kernel(const int* __restrict__ csum,
                                                         int* __restrict__ coff,
                                                         int NC) {
    __shared__ int s[128];
    const int t = threadIdx.x;
    const int v = (t < NC) ? csum[t] : 0;
    s[t] = v;
    __syncthreads();
    for (int off = 1; off < 128; off <<= 1) {
        const int val = s[t];
        const int add = (t >= off) ? s[t - off] : 0;
        __syncthreads();
        s[t] = val + add;
        __syncthreads();
    }
    if (t < NC) coff[t] = s[t] - v;
}

// Flags fill (NNODE domain): cmapx (slot or -1), nodes, meta[0]=T, meta[1]=Tu,
// gslot[g] = first slot of node-range group g (g=0..8).
__global__ __launch_bounds__(256) void fill_flags_kernel(
    const int* __restrict__ tmask, const int* __restrict__ coff,
    int* __restrict__ cmapx, int* __restrict__ nodes, int* __restrict__ meta,
    int* __restrict__ gslot) {
    __shared__ int sp[256];
    const int c  = blockIdx.x;
    const int t  = threadIdx.x;
    const int g0 = c * CHUNK + t * 4;
    int v[4];
#pragma unroll
    for (int i = 0; i < 4; ++i) v[i] = (g0 + i < NNODE) ? tmask[g0 + i] : 0;
    const int s = ((v[0] + v[1]) + (v[2] + v[3]));
    sp[t] = s;
    __syncthreads();
    for (int off = 1; off < 256; off <<= 1) {
        const int val = sp[t];
        const int add = (t >= off) ? sp[t - off] : 0;
        __syncthreads();
        sp[t] = val + add;
        __syncthreads();
    }
    int run = coff[c] + sp[t] - s;
#pragma unroll
    for (int i = 0; i < 4; ++i) {
        const int g = g0 + i;
        if (g < NNODE) {
            cmapx[g] = v[i] ? run : -1;
            if (v[i]) nodes[run] = g;
            if (g == USER_NUM) meta[1] = run;
            if (g % GROWS == 0) gslot[g / GROWS] = run;
            run += v[i];
        } else if (g == NNODE) {
            meta[0] = run;
            gslot[8] = run;
        }
    }
    if (g0 + 4 == NNODE) { meta[0] = run; gslot[8] = run; }
}

// Counts fill (N-domain, N multiple of 4): base + cursor; base[N]=total.
__global__ __launch_bounds__(256) void fill_kernel(const int* __restrict__ cnt,
                                                   const int* __restrict__ coff,
                                                   int* __restrict__ base,
                                                   int* __restrict__ cursor, int N) {
    __shared__ int sp[256];
    const int c  = blockIdx.x;
    const int t  = threadIdx.x;
    const int g0 = c * CHUNK + t * 4;
    int v[4];
#pragma unroll
    for (int i = 0; i < 4; ++i) v[i] = (g0 + i < N) ? cnt[g0 + i] : 0;
    const int s = ((v[0] + v[1]) + (v[2] + v[3]));
    sp[t] = s;
    __syncthreads();
    for (int off = 1; off < 256; off <<= 1) {
        const int val = sp[t];
        const int add = (t >= off) ? sp[t - off] : 0;
        __syncthreads();
        sp[t] = val + add;
        __syncthreads();
    }
    int run = coff[c] + sp[t] - s;
#pragma unroll
    for (int i = 0; i < 4; ++i) {
        const int g = g0 + i;
        if (g < N) {
            base[g]   = run;
            cursor[g] = run;
            run += v[i];
        }
    }
    if (g0 + 4 == N) base[N] = run;
}

// ---- Pass A: block-aggregated append of TOUCHED edges into 8 segments ------
// Segment g starts at g*GCAP. One global atomicAdd per (block, group);
// dense full-line writes. (Histogram is a separate LDS-based pass.)

__global__ __launch_bounds__(256) void append_kernel(
    const int* __restrict__ erow, const int* __restrict__ ecol,
    const float* __restrict__ eval, const int* __restrict__ cmapx,
    int* __restrict__ gcur, int* __restrict__ grow, int2* __restrict__ gpair,
    int E) {
    __shared__ int lcnt[8];
    __shared__ int lbase[8];
    const int t = threadIdx.x;
    if (t < 8) lcnt[t] = 0;
    __syncthreads();
    const int e0 = blockIdx.x * APB + t;
    int sl[EPT], c[EPT], gr[EPT], rk[EPT];
    float v[EPT];
#pragma unroll
    for (int i = 0; i < EPT; ++i) {
        const int e = e0 + 256 * i;
        gr[i] = -1;
        if (e < E) {
            const int r = erow[e];
            const int slot = cmapx[r];
            if (slot >= 0) {
                sl[i] = slot;
                c[i]  = ecol[e];
                v[i]  = eval[e];
                gr[i] = (r * 8) / NNODE;    // const div -> magic mul
                rk[i] = atomicAdd(&lcnt[gr[i]], 1);
            }
        }
    }
    __syncthreads();
    if (t < 8 && lcnt[t] > 0) lbase[t] = atomicAdd(&gcur[t], lcnt[t]);
    __syncthreads();
#pragma unroll
    for (int i = 0; i < EPT; ++i) {
        if (gr[i] >= 0) {
            const int pos = lbase[gr[i]] + rk[i];
            grow[pos]  = sl[i];             // compact slot
            gpair[pos] = make_int2(c[i], __float_as_int(v[i]));
        }
    }
}

// ---- Histogram: per-group LDS histogram over contiguous slot range ----------
// Group g's touched slots are [gslot[g], gslot[g+1]) — span <= GROWS (8750).
// 16 blocks/group accumulate in LDS, then merge with sequential coalesced
// global atomics (no random global atomics).

__global__ __launch_bounds__(256) void hist3_kernel(const int* __restrict__ grow,
                                                    const int* __restrict__ gcur,
                                                    const int* __restrict__ gslot,
                                                    int* __restrict__ cnt2) {
    __shared__ int hloc[GROWS];
    const int g    = blockIdx.x & 7;
    const int rank = blockIdx.x >> 3;       // 0..NB3-1
    const int slo  = gslot[g];
    const int span = gslot[g + 1] - slo;
    for (int i = threadIdx.x; i < span; i += 256) hloc[i] = 0;
    __syncthreads();
    const int hi = gcur[g];
    for (int i = g * GCAP + rank * 256 + (int)threadIdx.x; i < hi; i += NB3 * 256)
        atomicAdd(&hloc[grow[i] - slo], 1);
    __syncthreads();
    for (int i = threadIdx.x; i < span; i += 256) {
        const int v = hloc[i];
        if (v) atomicAdd(&cnt2[slo + i], v);
    }
}

// ---- Pass B: per-group CSR scatter ------------------------------------------

__global__ __launch_bounds__(256) void scatter2_kernel(
    const int* __restrict__ grow, const int2* __restrict__ gpair,
    const int* __restrict__ gcur, int* __restrict__ cursor2,
    int2* __restrict__ epair) {
    const int g    = blockIdx.x & 7;
    const int rank = blockIdx.x >> 3;       // 0..NS2-1
    const int hi = gcur[g];
    for (int i = g * GCAP + rank * 256 + (int)threadIdx.x; i < hi; i += NS2 * 256) {
        const int slot = grow[i];
        const int pos = atomicAdd(&cursor2[slot], 1);
        epair[pos] = gpair[i];
    }
}

// ---- SpMM over compact touched rows ----------------------------------------
// Stores a1 = lx + f (self term folded) and a2 = lx2, compact-indexed.

__global__ __launch_bounds__(256) void spmm_kernel(
    const float* __restrict__ ue, const float* __restrict__ ie,
    const int2* __restrict__ epair, const int* __restrict__ base2,
    const int* __restrict__ nodes, const int* __restrict__ meta,
    float* __restrict__ lx, float* __restrict__ lx2) {
    const int T = meta[0];
    const int lane = threadIdx.x & 63;
    int wv = (int)((blockIdx.x * blockDim.x + threadIdx.x) >> 6);
    wv = __builtin_amdgcn_readfirstlane(wv);
    const int nw = (int)((gridDim.x * blockDim.x) >> 6);
    for (int r = wv; r < T; r += nw) {
        const int jb = base2[r];
        const int je = base2[r + 1];
        float acc1 = 0.f, acc2 = 0.f;
        int j = jb;
        for (; j + 8 <= je; j += 8) {
            int2 p[8];
#pragma unroll
            for (int t = 0; t < 8; ++t) p[t] = epair[j + t];
            float f[8];
#pragma unroll
            for (int t = 0; t < 8; ++t) f[t] = feat_row(ue, ie, p[t].x)[lane];
#pragma unroll
            for (int t = 0; t < 8; ++t) {
                const float v = __int_as_float(p[t].y);
                acc1 = fmaf(v, f[t], acc1);
                acc2 = fmaf(v * f[t], f[t], acc2);
            }
        }
        for (; j + 4 <= je; j += 4) {
            int2 p[4];
#pragma unroll
            for (int t = 0; t < 4; ++t) p[t] = epair[j + t];
            float f[4];
#pragma unroll
            for (int t = 0; t < 4; ++t) f[t] = feat_row(ue, ie, p[t].x)[lane];
#pragma unroll
            for (int t = 0; t < 4; ++t) {
                const float v = __int_as_float(p[t].y);
                acc1 = fmaf(v, f[t], acc1);
                acc2 = fmaf(v * f[t], f[t], acc2);
            }
        }
        for (; j < je; ++j) {
            const int2 p = epair[j];
            const float f = feat_row(ue, ie, p.x)[lane];
            const float v = __int_as_float(p.y);
            acc1 = fmaf(v, f, acc1);
            acc2 = fmaf(v * f, f, acc2);
        }
        const int n = nodes[r];
        lx [(size_t)r * DD + lane] = acc1 + feat_row(ue, ie, n)[lane];
        lx2[(size_t)r * DD + lane] = acc2;
    }
}

// ---- Fused transform: GCN h (in LDS only) + MLP layer-1 partial ------------
// (round-13 structure: phase1 h -> LDS, phase2 part -> global)

template <int IS_USER>
__global__ __launch_bounds__(256) void xform_fused_kernel(
    const float* __restrict__ lx, const float* __restrict__ lx2,
    const float* __restrict__ fb,       // ue (users) or ie (items)
    const float* __restrict__ Wg1, const float* __restrict__ Wg2,
    const float* __restrict__ bg1, const float* __restrict__ bg2,
    const float* __restrict__ W1, const float* __restrict__ b1,
    float* __restrict__ part,
    const int* __restrict__ nodes, const int* __restrict__ meta) {
    const int Tu = meta[1];
    const int T  = meta[0];
    const int start = IS_USER ? 0  : Tu;
    const int lim   = IS_USER ? Tu : T;
    const int tb = start + (int)blockIdx.x * 64;
    if (tb >= lim) return;

    __shared__ float sXa[64 * DD];      // phase1: lx      phase2: h
    __shared__ float sXb[64 * DD];      // phase1: lx2     phase2: f
    __shared__ float sP [64 * DD];
    const int t     = threadIdx.x;
    const int lane  = t & 63;
    const int w     = t >> 6;
    const int khalf = (w & 1) * 32;
    const int rhalf = (w >> 1) * 32;

    float wva[32], wvb[32];
#pragma unroll
    for (int k = 0; k < 32; ++k) {
        wva[k] = Wg1[(khalf + k) * DD + lane];
        wvb[k] = Wg2[(khalf + k) * DD + lane];
    }

    float4* sXav = (float4*)sXa;
    float4* sXbv = (float4*)sXb;
    float4* sPv  = (float4*)sP;
#pragma unroll
    for (int i = 0; i < 4; ++i) {
        const int f4  = t + 256 * i;
        const int row = f4 >> 4;
        const int c   = f4 & 15;
        const int g   = min(tb + row, lim - 1);
        sXav[f4] = ((const float4*)(lx  + (size_t)g * DD))[c];
        sXbv[f4] = ((const float4*)(lx2 + (size_t)g * DD))[c];
        sPv[f4]  = make_float4(0.f, 0.f, 0.f, 0.f);
    }
    __syncthreads();

    // phase 1: h partials
#pragma unroll 2
    for (int r = 0; r < 32; ++r) {
        const int row = rhalf + r;
        const float* ra = &sXa[row * DD + khalf];
        const float* rb = &sXb[row * DD + khalf];
        float o0 = 0.f, o1 = 0.f, o2 = 0.f, o3 = 0.f;
#pragma unroll
        for (int q = 0; q < 8; ++q) {
            const float4 qa = *(const float4*)(ra + 4 * q);
            const float4 qb = *(const float4*)(rb + 4 * q);
            o0 = fmaf(qa.x, wva[4 * q + 0], o0);
            o1 = fmaf(qa.y, wva[4 * q + 1], o1);
            o0 = fmaf(qa.z, wva[4 * q + 2], o0);
            o1 = fmaf(qa.w, wva[4 * q + 3], o1);
            o2 = fmaf(qb.x, wvb[4 * q + 0], o2);
            o3 = fmaf(qb.y, wvb[4 * q + 1], o3);
            o2 = fmaf(qb.z, wvb[4 * q + 2], o2);
            o3 = fmaf(qb.w, wvb[4 * q + 3], o3);
        }
        atomicAdd(&sP[row * DD + lane], (o0 + o1) + (o2 + o3));
    }
    __syncthreads();

    // epilogue 1: h = lrelu(sP + bg1 + bg2) -> sXa; reset sP; stage f -> sXb
#pragma unroll
    for (int i = 0; i < 4; ++i) {
        const int f4  = t + 256 * i;
        const int row = f4 >> 4;
        const int c   = f4 & 15;
        float4 v = sPv[f4];
        const float4 ba = ((const float4*)bg1)[c];
        const float4 bb = ((const float4*)bg2)[c];
        v.x += ba.x + bb.x; v.y += ba.y + bb.y;
        v.z += ba.z + bb.z; v.w += ba.w + bb.w;
        v.x = (v.x > 0.f) ? v.x : 0.01f * v.x;
        v.y = (v.y > 0.f) ? v.y : 0.01f * v.y;
        v.z = (v.z > 0.f) ? v.z : 0.01f * v.z;
        v.w = (v.w > 0.f) ? v.w : 0.01f * v.w;
        sXav[f4] = v;                        // h
        sPv[f4]  = make_float4(0.f, 0.f, 0.f, 0.f);
        const int g = min(tb + row, lim - 1);
        int n = nodes[g];
        if (!IS_USER) n -= USER_NUM;
        sXbv[f4] = ((const float4*)(fb + (size_t)n * DD))[c];   // f
    }

    // phase-2 weights: sXa(h) pairs W1b, sXb(f) pairs W1a
    const float* W1a = W1 + (IS_USER ? 0 : 2 * DD * DD);
    const float* W1b = W1a + DD * DD;
#pragma unroll
    for (int k = 0; k < 32; ++k) {
        wva[k] = W1b[(khalf + k) * DD + lane];
        wvb[k] = W1a[(khalf + k) * DD + lane];
    }
    __syncthreads();

    // phase 2: part partials
#pragma unroll 2
    for (int r = 0; r < 32; ++r) {
        const int row = rhalf + r;
        const float* ra = &sXa[row * DD + khalf];
        const float* rb = &sXb[row * DD + khalf];
        float o0 = 0.f, o1 = 0.f, o2 = 0.f, o3 = 0.f;
#pragma unroll
        for (int q = 0; q < 8; ++q) {
            const float4 qa = *(const float4*)(ra + 4 * q);
            const float4 qb = *(const float4*)(rb + 4 * q);
            o0 = fmaf(qa.x, wva[4 * q + 0], o0);
            o1 = fmaf(qa.y, wva[4 * q + 1], o1);
            o0 = fmaf(qa.z, wva[4 * q + 2], o0);
            o1 = fmaf(qa.w, wva[4 * q + 3], o1);
            o2 = fmaf(qb.x, wvb[4 * q + 0], o2);
            o3 = fmaf(qb.y, wvb[4 * q + 1], o3);
            o2 = fmaf(qb.z, wvb[4 * q + 2], o2);
            o3 = fmaf(qb.w, wvb[4 * q + 3], o3);
        }
        atomicAdd(&sP[row * DD + lane], (o0 + o1) + (o2 + o3));
    }
    __syncthreads();

    // epilogue 2: part = sP (+ b1 for users)
    float4* outv = (float4*)part;
#pragma unroll
    for (int i = 0; i < 4; ++i) {
        const int f4  = t + 256 * i;
        const int row = f4 >> 4;
        const int c   = f4 & 15;
        const int g   = tb + row;
        float4 v = sPv[f4];
        if (IS_USER) {
            const float4 b = ((const float4*)b1)[c];
            v.x += b.x; v.y += b.y; v.z += b.z; v.w += b.w;
        }
        if (g < lim) outv[(size_t)g * 16 + c] = v;
    }
}

// ---- Per-sample MLP: o1 = relu(part_u + part_i); layers 2,3 ----------------

__global__ __launch_bounds__(256) void mlp_kernel(
    const float* __restrict__ part, const int* __restrict__ cmapx,
    const float* __restrict__ W2, const float* __restrict__ b2,
    const float* __restrict__ W3, const float* __restrict__ b3,
    const int* __restrict__ uid, const int* __restrict__ iid,
    float* __restrict__ out, int B) {
    __shared__ float sW2[DD * 32];
    __shared__ float sW3[32];
    for (int i = threadIdx.x; i < DD * 32; i += 256) sW2[i] = W2[i];
    if (threadIdx.x < 32) sW3[threadIdx.x] = W3[threadIdx.x];
    __syncthreads();
    const int lane = threadIdx.x & 63;
    const int wave = (int)((blockIdx.x * blockDim.x + threadIdx.x) >> 6);
    const int nw   = (int)((gridDim.x * blockDim.x) >> 6);
    const float bias2 = b2[lane & 31];
    const float w3v   = sW3[lane & 31];
    const float bias3 = b3[0];
    for (int s = wave; s < B; s += nw) {
        const int su = cmapx[uid[s]];
        const int si = cmapx[USER_NUM + iid[s]];
        const float pu = part[(size_t)su * DD + lane];
        const float pi = part[(size_t)si * DD + lane];
        const float x  = pu + pi;
        const float o1 = (x > 0.f) ? x : 0.f;
        float acc_a = bias2, acc_b = 0.f;
#pragma unroll
        for (int k = 0; k < DD; k += 2) {
            acc_a = fmaf(__shfl(o1, k),     sW2[k * 32 + (lane & 31)],       acc_a);
            acc_b = fmaf(__shfl(o1, k + 1), sW2[(k + 1) * 32 + (lane & 31)], acc_b);
        }
        const float a2 = acc_a + acc_b;
        const float o2 = (a2 > 0.f) ? a2 : 0.f;
        float p = o2 * w3v;
        p += __shfl_xor(p, 1);
        p += __shfl_xor(p, 2);
        p += __shfl_xor(p, 4);
        p += __shfl_xor(p, 8);
        p += __shfl_xor(p, 16);
        if (lane == 0) out[s] = p + bias3;
    }
}

extern "C" void kernel_launch(void* const* d_in, const int* in_sizes, int n_in,
                              void* d_out, int out_size, void* d_ws, size_t ws_size,
                              hipStream_t stream) {
    const float* ue   = (const float*)d_in[0];
    const float* ie   = (const float*)d_in[1];
    const int*   erow = (const int*)d_in[2];
    const int*   ecol = (const int*)d_in[3];
    const float* evalp= (const float*)d_in[4];
    const float* Wg1  = (const float*)d_in[5];
    const float* bg1  = (const float*)d_in[6];
    const float* Wg2  = (const float*)d_in[7];
    const float* bg2  = (const float*)d_in[8];
    const float* W1   = (const float*)d_in[9];
    const float* b1   = (const float*)d_in[10];
    const float* W2   = (const float*)d_in[11];
    const float* b2   = (const float*)d_in[12];
    const float* W3   = (const float*)d_in[13];
    const float* b3   = (const float*)d_in[14];
    const int*   uid  = (const int*)d_in[15];
    const int*   iid  = (const int*)d_in[16];
    float* out = (float*)d_out;

    const int E = in_sizes[2];
    const int B = in_sizes[15];

    const int TU_MAX = (B < USER_NUM) ? B : USER_NUM;   // touched users <= B
    const int TI_MAX = (B < ITEM_NUM) ? B : ITEM_NUM;   // touched items <= B

    // workspace layout (~49.5 MB peak):
    //  [A: 32MB  lx|lx2|part (8MB each, compact T_CAP rows) + 8MB spare]
    //    - during CSR build, grow(10.5MB)+gpair(21MB) overlay region A
    //      (both dead before spmm writes lx/lx2)
    //  [B: epair 16MB]
    //  [C: misc ints ~1.2MB]
    char* ws = (char*)d_ws;
    const size_t ndc = (size_t)T_CAP * DD;              // 8MB per array
    float* lx    = (float*)ws;
    float* lx2   = lx + ndc;
    float* part  = lx2 + ndc;
    int*   grow  = (int*)ws;                            // 8*GCAP ints (10.5MB)
    int2*  gpair = (int2*)(ws + 11u * 1024 * 1024);     // 8*GCAP int2 (21MB)
    char*  tail  = ws + 32u * 1024 * 1024;
    int2*  epair = (int2*)tail;                         // E int2 = 16MB
    int*   mi    = (int*)(tail + (size_t)E * sizeof(int2));
    int*   cnt2    = mi;                                // T_CAP
    int*   cursor2 = cnt2 + T_CAP;                      // T_CAP
    int*   base2   = cursor2 + T_CAP;                   // T_CAP+1
    int*   tmask   = base2 + T_CAP + 1;                 // NNODE
    int*   cmapx   = tmask + NNODE;                     // NNODE
    int*   nodes   = cmapx + NNODE;                     // T_CAP
    int*   csum    = nodes + T_CAP;                     // 128
    int*   coff    = csum + 128;                        // 128
    int*   gcur    = coff + 128;                        // 8
    int*   meta    = gcur + 8;                          // [0]=T, [1]=Tu
    int*   gslot   = meta + 8;                          // 9 ints

    zero_kernel<<<512, 256, 0, stream>>>(cnt2, tmask, gcur);
    mark_kernel<<<(B + 255) / 256, 256, 0, stream>>>(uid, iid, tmask, B);
    chunksum_kernel<<<NCHUNK, 256, 0, stream>>>(tmask, csum, NNODE);
    scan_small_kernel<<<1, 128, 0, stream>>>(csum, coff, NCHUNK);
    fill_flags_kernel<<<NCHUNK, 256, 0, stream>>>(tmask, coff, cmapx, nodes,
                                                  meta, gslot);
    append_kernel<<<(E + APB - 1) / APB, 256, 0, stream>>>(
        erow, ecol, evalp, cmapx, gcur, grow, gpair, E);
    hist3_kernel<<<8 * NB3, 256, 0, stream>>>(grow, gcur, gslot, cnt2);
    chunksum_kernel<<<NCHUNK2, 256, 0, stream>>>(cnt2, csum, T_CAP);
    scan_small_kernel<<<1, 128, 0, stream>>>(csum, coff, NCHUNK2);
    fill_kernel<<<NCHUNK2, 256, 0, stream>>>(cnt2, coff, base2, cursor2, T_CAP);
    scatter2_kernel<<<8 * NS2, 256, 0, stream>>>(grow, gpair, gcur, cursor2, epair);
    spmm_kernel<<<4096, 256, 0, stream>>>(ue, ie, epair, base2, nodes, meta,
                                          lx, lx2);

    // fused: h in LDS, part to global (users then items)
    xform_fused_kernel<1><<<(TU_MAX + 63) / 64, 256, 0, stream>>>(
        lx, lx2, ue, Wg1, Wg2, bg1, bg2, W1, b1, part, nodes, meta);
    xform_fused_kernel<0><<<(TI_MAX + 63) / 64, 256, 0, stream>>>(
        lx, lx2, ie, Wg1, Wg2, bg1, bg2, W1, b1, part, nodes, meta);

    mlp_kernel<<<1024, 256, 0, stream>>>(part, cmapx, W2, b2, W3, b3,
                                         uid, iid, out, B);
}

// Round 15
// 208.012 us; speedup vs baseline: 2.3150x; 1.1091x over previous
//
#include <hip/hip_runtime.h>
#include <hip/hip_bf16.h>

#define USER_NUM 50000
#define ITEM_NUM 20000
#define NNODE    70000
#define DD       64
#define CHUNK    1024
#define NCHUNK   ((NNODE + CHUNK - 1) / CHUNK)   // 69
#define GROWS    (NNODE / 8)                     // 8750 rows per coarse group
#define APB      2048                            // append: edges per block
#define EPT      8                               // append: edges per thread
#define NS2      128                             // scatter2 stripes per group
#define NB3      16                              // hist3 blocks per group
#define T_CAP    32768                           // max touched slots (B=16384)
#define NCHUNK2  (T_CAP / CHUNK)                 // 32
#define GCAP     327680                          // per-group edge capacity
#define RT       32                              // xform tile rows

__device__ __forceinline__ const float* feat_row(const float* __restrict__ ue,
                                                 const float* __restrict__ ie, int n) {
    return (n < USER_NUM) ? (ue + (size_t)n * DD)
                          : (ie + (size_t)(n - USER_NUM) * DD);
}

// ---- init: zero cnt2/tmask, seed gcur --------------------------------------

__global__ __launch_bounds__(256) void zero_kernel(int* __restrict__ cnt2,
                                                   int* __restrict__ tmask,
                                                   int* __restrict__ gcur) {
    const int tid    = blockIdx.x * 256 + (int)threadIdx.x;
    const int stride = gridDim.x * 256;
    for (int i = tid; i < T_CAP; i += stride) cnt2[i] = 0;
    for (int i = tid; i < NNODE; i += stride) tmask[i] = 0;
    if (tid < 8) gcur[tid] = tid * GCAP;
}

// ---- Touched-node marking --------------------------------------------------

__global__ __launch_bounds__(256) void mark_kernel(const int* __restrict__ uid,
                                                   const int* __restrict__ iid,
                                                   int* __restrict__ tmask, int B) {
    const int stride = gridDim.x * blockDim.x;
    for (int s = blockIdx.x * blockDim.x + threadIdx.x; s < B; s += stride) {
        tmask[uid[s]] = 1;                       // racing same-value stores: benign
        tmask[USER_NUM + iid[s]] = 1;
    }
}

// ---- Generic 3-phase scan pieces (domain size N as arg) --------------------

__global__ __launch_bounds__(256) void chunksum_kernel(const int* __restrict__ arr,
                                                       int* __restrict__ csum, int N) {
    __shared__ int red[4];
    const int c = blockIdx.x;
    const int t = threadIdx.x;
    int s = 0;
#pragma unroll
    for (int i = 0; i < 4; ++i) {
        const int idx = c * CHUNK + t + 256 * i;
        s += (idx < N) ? arr[idx] : 0;
    }
#pragma unroll
    for (int off = 32; off; off >>= 1) s += __shfl_down(s, off);
    if ((t & 63) == 0) red[t >> 6] = s;
    __syncthreads();
    if (t == 0) csum[c] = red[0] + red[1] + red[2] + red[3];
}

__global__ __launch_bounds__(128) void scan_small_kernel(const int* __restrict__ csum,
                                                         int* __restrict__ coff,
                                                         int NC) {
    __shared__ int s[128];
    const int t = threadIdx.x;
    const int v = (t < NC) ? csum[t] : 0;
    s[t] = v;
    __syncthreads();
    for (int off = 1; off < 128; off <<= 1) {
        const int val = s[t];
        const int add = (t >= off) ? s[t - off] : 0;
        __syncthreads();
        s[t] = val + add;
        __syncthreads();
    }
    if (t < NC) coff[t] = s[t] - v;
}

// Flags fill (NNODE domain): cmapx (slot or -1), nodes, meta[0]=T, meta[1]=Tu,
// gslot[g] = first slot of node-range group g (g=0..8).
__global__ __launch_bounds__(256) void fill_flags_kernel(
    const int* __restrict__ tmask, const int* __restrict__ coff,
    int* __restrict__ cmapx, int* __restrict__ nodes, int* __restrict__ meta,
    int* __restrict__ gslot) {
    __shared__ int sp[256];
    const int c  = blockIdx.x;
    const int t  = threadIdx.x;
    const int g0 = c * CHUNK + t * 4;
    int v[4];
#pragma unroll
    for (int i = 0; i < 4; ++i) v[i] = (g0 + i < NNODE) ? tmask[g0 + i] : 0;
    const int s = ((v[0] + v[1]) + (v[2] + v[3]));
    sp[t] = s;
    __syncthreads();
    for (int off = 1; off < 256; off <<= 1) {
        const int val = sp[t];
        const int add = (t >= off) ? sp[t - off] : 0;
        __syncthreads();
        sp[t] = val + add;
        __syncthreads();
    }
    int run = coff[c] + sp[t] - s;
#pragma unroll
    for (int i = 0; i < 4; ++i) {
        const int g = g0 + i;
        if (g < NNODE) {
            cmapx[g] = v[i] ? run : -1;
            if (v[i]) nodes[run] = g;
            if (g == USER_NUM) meta[1] = run;
            if (g % GROWS == 0) gslot[g / GROWS] = run;
            run += v[i];
        } else if (g == NNODE) {
            meta[0] = run;
            gslot[8] = run;
        }
    }
    if (g0 + 4 == NNODE) { meta[0] = run; gslot[8] = run; }
}

// Counts fill (N-domain, N multiple of 4): base + cursor; base[N]=total.
__global__ __launch_bounds__(256) void fill_kernel(const int* __restrict__ cnt,
                                                   const int* __restrict__ coff,
                                                   int* __restrict__ base,
                                                   int* __restrict__ cursor, int N) {
    __shared__ int sp[256];
    const int c  = blockIdx.x;
    const int t  = threadIdx.x;
    const int g0 = c * CHUNK + t * 4;
    int v[4];
#pragma unroll
    for (int i = 0; i < 4; ++i) v[i] = (g0 + i < N) ? cnt[g0 + i] : 0;
    const int s = ((v[0] + v[1]) + (v[2] + v[3]));
    sp[t] = s;
    __syncthreads();
    for (int off = 1; off < 256; off <<= 1) {
        const int val = sp[t];
        const int add = (t >= off) ? sp[t - off] : 0;
        __syncthreads();
        sp[t] = val + add;
        __syncthreads();
    }
    int run = coff[c] + sp[t] - s;
#pragma unroll
    for (int i = 0; i < 4; ++i) {
        const int g = g0 + i;
        if (g < N) {
            base[g]   = run;
            cursor[g] = run;
            run += v[i];
        }
    }
    if (g0 + 4 == N) base[N] = run;
}

// ---- Pass A: block-aggregated append of TOUCHED edges into 8 segments ------

__global__ __launch_bounds__(256) void append_kernel(
    const int* __restrict__ erow, const int* __restrict__ ecol,
    const float* __restrict__ eval, const int* __restrict__ cmapx,
    int* __restrict__ gcur, int* __restrict__ grow, int2* __restrict__ gpair,
    int E) {
    __shared__ int lcnt[8];
    __shared__ int lbase[8];
    const int t = threadIdx.x;
    if (t < 8) lcnt[t] = 0;
    __syncthreads();
    const int e0 = blockIdx.x * APB + t;
    int sl[EPT], c[EPT], gr[EPT], rk[EPT];
    float v[EPT];
#pragma unroll
    for (int i = 0; i < EPT; ++i) {
        const int e = e0 + 256 * i;
        gr[i] = -1;
        if (e < E) {
            const int r = erow[e];
            const int slot = cmapx[r];
            if (slot >= 0) {
                sl[i] = slot;
                c[i]  = ecol[e];
                v[i]  = eval[e];
                gr[i] = (r * 8) / NNODE;    // const div -> magic mul
                rk[i] = atomicAdd(&lcnt[gr[i]], 1);
            }
        }
    }
    __syncthreads();
    if (t < 8 && lcnt[t] > 0) lbase[t] = atomicAdd(&gcur[t], lcnt[t]);
    __syncthreads();
#pragma unroll
    for (int i = 0; i < EPT; ++i) {
        if (gr[i] >= 0) {
            const int pos = lbase[gr[i]] + rk[i];
            grow[pos]  = sl[i];             // compact slot
            gpair[pos] = make_int2(c[i], __float_as_int(v[i]));
        }
    }
}

// ---- Histogram: per-group LDS histogram over contiguous slot range ----------

__global__ __launch_bounds__(256) void hist3_kernel(const int* __restrict__ grow,
                                                    const int* __restrict__ gcur,
                                                    const int* __restrict__ gslot,
                                                    int* __restrict__ cnt2) {
    __shared__ int hloc[GROWS];
    const int g    = blockIdx.x & 7;
    const int rank = blockIdx.x >> 3;       // 0..NB3-1
    const int slo  = gslot[g];
    const int span = gslot[g + 1] - slo;
    for (int i = threadIdx.x; i < span; i += 256) hloc[i] = 0;
    __syncthreads();
    const int hi = gcur[g];
    for (int i = g * GCAP + rank * 256 + (int)threadIdx.x; i < hi; i += NB3 * 256)
        atomicAdd(&hloc[grow[i] - slo], 1);
    __syncthreads();
    for (int i = threadIdx.x; i < span; i += 256) {
        const int v = hloc[i];
        if (v) atomicAdd(&cnt2[slo + i], v);
    }
}

// ---- Pass B: per-group CSR scatter ------------------------------------------

__global__ __launch_bounds__(256) void scatter2_kernel(
    const int* __restrict__ grow, const int2* __restrict__ gpair,
    const int* __restrict__ gcur, int* __restrict__ cursor2,
    int2* __restrict__ epair) {
    const int g    = blockIdx.x & 7;
    const int rank = blockIdx.x >> 3;       // 0..NS2-1
    const int hi = gcur[g];
    for (int i = g * GCAP + rank * 256 + (int)threadIdx.x; i < hi; i += NS2 * 256) {
        const int slot = grow[i];
        const int pos = atomicAdd(&cursor2[slot], 1);
        epair[pos] = gpair[i];
    }
}

// ---- SpMM over compact touched rows ----------------------------------------

__global__ __launch_bounds__(256) void spmm_kernel(
    const float* __restrict__ ue, const float* __restrict__ ie,
    const int2* __restrict__ epair, const int* __restrict__ base2,
    const int* __restrict__ nodes, const int* __restrict__ meta,
    float* __restrict__ lx, float* __restrict__ lx2) {
    const int T = meta[0];
    const int lane = threadIdx.x & 63;
    int wv = (int)((blockIdx.x * blockDim.x + threadIdx.x) >> 6);
    wv = __builtin_amdgcn_readfirstlane(wv);
    const int nw = (int)((gridDim.x * blockDim.x) >> 6);
    for (int r = wv; r < T; r += nw) {
        const int jb = base2[r];
        const int je = base2[r + 1];
        float acc1 = 0.f, acc2 = 0.f;
        int j = jb;
        for (; j + 8 <= je; j += 8) {
            int2 p[8];
#pragma unroll
            for (int t = 0; t < 8; ++t) p[t] = epair[j + t];
            float f[8];
#pragma unroll
            for (int t = 0; t < 8; ++t) f[t] = feat_row(ue, ie, p[t].x)[lane];
#pragma unroll
            for (int t = 0; t < 8; ++t) {
                const float v = __int_as_float(p[t].y);
                acc1 = fmaf(v, f[t], acc1);
                acc2 = fmaf(v * f[t], f[t], acc2);
            }
        }
        for (; j + 4 <= je; j += 4) {
            int2 p[4];
#pragma unroll
            for (int t = 0; t < 4; ++t) p[t] = epair[j + t];
            float f[4];
#pragma unroll
            for (int t = 0; t < 4; ++t) f[t] = feat_row(ue, ie, p[t].x)[lane];
#pragma unroll
            for (int t = 0; t < 4; ++t) {
                const float v = __int_as_float(p[t].y);
                acc1 = fmaf(v, f[t], acc1);
                acc2 = fmaf(v * f[t], f[t], acc2);
            }
        }
        for (; j < je; ++j) {
            const int2 p = epair[j];
            const float f = feat_row(ue, ie, p.x)[lane];
            const float v = __int_as_float(p.y);
            acc1 = fmaf(v, f, acc1);
            acc2 = fmaf(v * f, f, acc2);
        }
        const int n = nodes[r];
        lx [(size_t)r * DD + lane] = acc1 + feat_row(ue, ie, n)[lane];
        lx2[(size_t)r * DD + lane] = acc2;
    }
}

// ---- Fused transform, combined user+item, 32-row tiles ----------------------
// blockIdx < nTilesU -> user tile; else item tile. Per tile:
//   phase1: h = lrelu(lx@Wg1 + lx2@Wg2 + bg1 + bg2)   -> kept in LDS
//   phase2: part = f@W1a + h@W1b (+ b1 for users)     -> global
// 24KB LDS, 1024 blocks -> ~4 blocks/CU (vs round-14's 1/CU at 64-row tiles).

__global__ __launch_bounds__(256) void xform_fused_kernel(
    const float* __restrict__ lx, const float* __restrict__ lx2,
    const float* __restrict__ ue, const float* __restrict__ ie,
    const float* __restrict__ Wg1, const float* __restrict__ Wg2,
    const float* __restrict__ bg1, const float* __restrict__ bg2,
    const float* __restrict__ W1, const float* __restrict__ b1,
    float* __restrict__ part,
    const int* __restrict__ nodes, const int* __restrict__ meta, int nTilesU) {
    const int Tu = meta[1];
    const int T  = meta[0];
    const bool isU   = (int)blockIdx.x < nTilesU;
    const int tileIx = isU ? blockIdx.x : (blockIdx.x - nTilesU);
    const int start  = isU ? 0  : Tu;
    const int lim    = isU ? Tu : T;
    const int tb     = start + tileIx * RT;
    if (tb >= lim) return;
    const float* fb = isU ? ue : ie;

    __shared__ float sXa[RT * DD];      // phase1: lx      phase2: h
    __shared__ float sXb[RT * DD];      // phase1: lx2     phase2: f
    __shared__ float sP [RT * DD];
    const int t     = threadIdx.x;
    const int lane  = t & 63;
    const int w     = t >> 6;
    const int khalf = (w & 1) * 32;
    const int rhalf = (w >> 1) * (RT / 2);

    float wva[32], wvb[32];
#pragma unroll
    for (int k = 0; k < 32; ++k) {
        wva[k] = Wg1[(khalf + k) * DD + lane];
        wvb[k] = Wg2[(khalf + k) * DD + lane];
    }

    float4* sXav = (float4*)sXa;
    float4* sXbv = (float4*)sXb;
    float4* sPv  = (float4*)sP;
#pragma unroll
    for (int i = 0; i < RT / 16; ++i) {
        const int f4  = t + 256 * i;
        const int row = f4 >> 4;
        const int c   = f4 & 15;
        const int g   = min(tb + row, lim - 1);
        sXav[f4] = ((const float4*)(lx  + (size_t)g * DD))[c];
        sXbv[f4] = ((const float4*)(lx2 + (size_t)g * DD))[c];
        sPv[f4]  = make_float4(0.f, 0.f, 0.f, 0.f);
    }
    __syncthreads();

    // phase 1: h partials
#pragma unroll 2
    for (int r = 0; r < RT / 2; ++r) {
        const int row = rhalf + r;
        const float* ra = &sXa[row * DD + khalf];
        const float* rb = &sXb[row * DD + khalf];
        float o0 = 0.f, o1 = 0.f, o2 = 0.f, o3 = 0.f;
#pragma unroll
        for (int q = 0; q < 8; ++q) {
            const float4 qa = *(const float4*)(ra + 4 * q);
            const float4 qb = *(const float4*)(rb + 4 * q);
            o0 = fmaf(qa.x, wva[4 * q + 0], o0);
            o1 = fmaf(qa.y, wva[4 * q + 1], o1);
            o0 = fmaf(qa.z, wva[4 * q + 2], o0);
            o1 = fmaf(qa.w, wva[4 * q + 3], o1);
            o2 = fmaf(qb.x, wvb[4 * q + 0], o2);
            o3 = fmaf(qb.y, wvb[4 * q + 1], o3);
            o2 = fmaf(qb.z, wvb[4 * q + 2], o2);
            o3 = fmaf(qb.w, wvb[4 * q + 3], o3);
        }
        atomicAdd(&sP[row * DD + lane], (o0 + o1) + (o2 + o3));
    }
    __syncthreads();

    // epilogue 1: h = lrelu(sP + bg1 + bg2) -> sXa; reset sP; stage f -> sXb
#pragma unroll
    for (int i = 0; i < RT / 16; ++i) {
        const int f4  = t + 256 * i;
        const int row = f4 >> 4;
        const int c   = f4 & 15;
        float4 v = sPv[f4];
        const float4 ba = ((const float4*)bg1)[c];
        const float4 bb = ((const float4*)bg2)[c];
        v.x += ba.x + bb.x; v.y += ba.y + bb.y;
        v.z += ba.z + bb.z; v.w += ba.w + bb.w;
        v.x = (v.x > 0.f) ? v.x : 0.01f * v.x;
        v.y = (v.y > 0.f) ? v.y : 0.01f * v.y;
        v.z = (v.z > 0.f) ? v.z : 0.01f * v.z;
        v.w = (v.w > 0.f) ? v.w : 0.01f * v.w;
        sXav[f4] = v;                        // h
        sPv[f4]  = make_float4(0.f, 0.f, 0.f, 0.f);
        const int g = min(tb + row, lim - 1);
        int n = nodes[g];
        if (!isU) n -= USER_NUM;
        sXbv[f4] = ((const float4*)(fb + (size_t)n * DD))[c];   // f
    }

    // phase-2 weights: sXa(h) pairs W1b, sXb(f) pairs W1a
    const float* W1a = W1 + (isU ? 0 : 2 * DD * DD);
    const float* W1b = W1a + DD * DD;
#pragma unroll
    for (int k = 0; k < 32; ++k) {
        wva[k] = W1b[(khalf + k) * DD + lane];
        wvb[k] = W1a[(khalf + k) * DD + lane];
    }
    __syncthreads();

    // phase 2: part partials
#pragma unroll 2
    for (int r = 0; r < RT / 2; ++r) {
        const int row = rhalf + r;
        const float* ra = &sXa[row * DD + khalf];
        const float* rb = &sXb[row * DD + khalf];
        float o0 = 0.f, o1 = 0.f, o2 = 0.f, o3 = 0.f;
#pragma unroll
        for (int q = 0; q < 8; ++q) {
            const float4 qa = *(const float4*)(ra + 4 * q);
            const float4 qb = *(const float4*)(rb + 4 * q);
            o0 = fmaf(qa.x, wva[4 * q + 0], o0);
            o1 = fmaf(qa.y, wva[4 * q + 1], o1);
            o0 = fmaf(qa.z, wva[4 * q + 2], o0);
            o1 = fmaf(qa.w, wva[4 * q + 3], o1);
            o2 = fmaf(qb.x, wvb[4 * q + 0], o2);
            o3 = fmaf(qb.y, wvb[4 * q + 1], o3);
            o2 = fmaf(qb.z, wvb[4 * q + 2], o2);
            o3 = fmaf(qb.w, wvb[4 * q + 3], o3);
        }
        atomicAdd(&sP[row * DD + lane], (o0 + o1) + (o2 + o3));
    }
    __syncthreads();

    // epilogue 2: part = sP (+ b1 for users)
    float4* outv = (float4*)part;
#pragma unroll
    for (int i = 0; i < RT / 16; ++i) {
        const int f4  = t + 256 * i;
        const int row = f4 >> 4;
        const int c   = f4 & 15;
        const int g   = tb + row;
        float4 v = sPv[f4];
        if (isU) {
            const float4 b = ((const float4*)b1)[c];
            v.x += b.x; v.y += b.y; v.z += b.z; v.w += b.w;
        }
        if (g < lim) outv[(size_t)g * 16 + c] = v;
    }
}

// ---- Per-sample MLP: o1 = relu(part_u + part_i); layers 2,3 ----------------

__global__ __launch_bounds__(256) void mlp_kernel(
    const float* __restrict__ part, const int* __restrict__ cmapx,
    const float* __restrict__ W2, const float* __restrict__ b2,
    const float* __restrict__ W3, const float* __restrict__ b3,
    const int* __restrict__ uid, const int* __restrict__ iid,
    float* __restrict__ out, int B) {
    __shared__ float sW2[DD * 32];
    __shared__ float sW3[32];
    for (int i = threadIdx.x; i < DD * 32; i += 256) sW2[i] = W2[i];
    if (threadIdx.x < 32) sW3[threadIdx.x] = W3[threadIdx.x];
    __syncthreads();
    const int lane = threadIdx.x & 63;
    const int wave = (int)((blockIdx.x * blockDim.x + threadIdx.x) >> 6);
    const int nw   = (int)((gridDim.x * blockDim.x) >> 6);
    const float bias2 = b2[lane & 31];
    const float w3v   = sW3[lane & 31];
    const float bias3 = b3[0];
    for (int s = wave; s < B; s += nw) {
        const int su = cmapx[uid[s]];
        const int si = cmapx[USER_NUM + iid[s]];
        const float pu = part[(size_t)su * DD + lane];
        const float pi = part[(size_t)si * DD + lane];
        const float x  = pu + pi;
        const float o1 = (x > 0.f) ? x : 0.f;
        float acc_a = bias2, acc_b = 0.f;
#pragma unroll
        for (int k = 0; k < DD; k += 2) {
            acc_a = fmaf(__shfl(o1, k),     sW2[k * 32 + (lane & 31)],       acc_a);
            acc_b = fmaf(__shfl(o1, k + 1), sW2[(k + 1) * 32 + (lane & 31)], acc_b);
        }
        const float a2 = acc_a + acc_b;
        const float o2 = (a2 > 0.f) ? a2 : 0.f;
        float p = o2 * w3v;
        p += __shfl_xor(p, 1);
        p += __shfl_xor(p, 2);
        p += __shfl_xor(p, 4);
        p += __shfl_xor(p, 8);
        p += __shfl_xor(p, 16);
        if (lane == 0) out[s] = p + bias3;
    }
}

extern "C" void kernel_launch(void* const* d_in, const int* in_sizes, int n_in,
                              void* d_out, int out_size, void* d_ws, size_t ws_size,
                              hipStream_t stream) {
    const float* ue   = (const float*)d_in[0];
    const float* ie   = (const float*)d_in[1];
    const int*   erow = (const int*)d_in[2];
    const int*   ecol = (const int*)d_in[3];
    const float* evalp= (const float*)d_in[4];
    const float* Wg1  = (const float*)d_in[5];
    const float* bg1  = (const float*)d_in[6];
    const float* Wg2  = (const float*)d_in[7];
    const float* bg2  = (const float*)d_in[8];
    const float* W1   = (const float*)d_in[9];
    const float* b1   = (const float*)d_in[10];
    const float* W2   = (const float*)d_in[11];
    const float* b2   = (const float*)d_in[12];
    const float* W3   = (const float*)d_in[13];
    const float* b3   = (const float*)d_in[14];
    const int*   uid  = (const int*)d_in[15];
    const int*   iid  = (const int*)d_in[16];
    float* out = (float*)d_out;

    const int E = in_sizes[2];
    const int B = in_sizes[15];

    const int TU_MAX = (B < USER_NUM) ? B : USER_NUM;   // touched users <= B
    const int TI_MAX = (B < ITEM_NUM) ? B : ITEM_NUM;   // touched items <= B
    const int nTilesU = (TU_MAX + RT - 1) / RT;
    const int nTilesI = (TI_MAX + RT - 1) / RT;

    // workspace layout (~49.5 MB peak):
    //  [A: 32MB  lx|lx2|part (8MB each, compact T_CAP rows) + 8MB spare]
    //    - during CSR build, grow(10.5MB)+gpair(21MB) overlay region A
    //      (both dead before spmm writes lx/lx2)
    //  [B: epair 16MB]
    //  [C: misc ints ~1.2MB]
    char* ws = (char*)d_ws;
    const size_t ndc = (size_t)T_CAP * DD;              // 8MB per array
    float* lx    = (float*)ws;
    float* lx2   = lx + ndc;
    float* part  = lx2 + ndc;
    int*   grow  = (int*)ws;                            // 8*GCAP ints (10.5MB)
    int2*  gpair = (int2*)(ws + 11u * 1024 * 1024);     // 8*GCAP int2 (21MB)
    char*  tail  = ws + 32u * 1024 * 1024;
    int2*  epair = (int2*)tail;                         // E int2 = 16MB
    int*   mi    = (int*)(tail + (size_t)E * sizeof(int2));
    int*   cnt2    = mi;                                // T_CAP
    int*   cursor2 = cnt2 + T_CAP;                      // T_CAP
    int*   base2   = cursor2 + T_CAP;                   // T_CAP+1
    int*   tmask   = base2 + T_CAP + 1;                 // NNODE
    int*   cmapx   = tmask + NNODE;                     // NNODE
    int*   nodes   = cmapx + NNODE;                     // T_CAP
    int*   csum    = nodes + T_CAP;                     // 128
    int*   coff    = csum + 128;                        // 128
    int*   gcur    = coff + 128;                        // 8
    int*   meta    = gcur + 8;                          // [0]=T, [1]=Tu
    int*   gslot   = meta + 8;                          // 9 ints

    zero_kernel<<<512, 256, 0, stream>>>(cnt2, tmask, gcur);
    mark_kernel<<<(B + 255) / 256, 256, 0, stream>>>(uid, iid, tmask, B);
    chunksum_kernel<<<NCHUNK, 256, 0, stream>>>(tmask, csum, NNODE);
    scan_small_kernel<<<1, 128, 0, stream>>>(csum, coff, NCHUNK);
    fill_flags_kernel<<<NCHUNK, 256, 0, stream>>>(tmask, coff, cmapx, nodes,
                                                  meta, gslot);
    append_kernel<<<(E + APB - 1) / APB, 256, 0, stream>>>(
        erow, ecol, evalp, cmapx, gcur, grow, gpair, E);
    hist3_kernel<<<8 * NB3, 256, 0, stream>>>(grow, gcur, gslot, cnt2);
    chunksum_kernel<<<NCHUNK2, 256, 0, stream>>>(cnt2, csum, T_CAP);
    scan_small_kernel<<<1, 128, 0, stream>>>(csum, coff, NCHUNK2);
    fill_kernel<<<NCHUNK2, 256, 0, stream>>>(cnt2, coff, base2, cursor2, T_CAP);
    scatter2_kernel<<<8 * NS2, 256, 0, stream>>>(grow, gpair, gcur, cursor2, epair);
    spmm_kernel<<<4096, 256, 0, stream>>>(ue, ie, epair, base2, nodes, meta,
                                          lx, lx2);

    // fused transform: one launch covers user + item tiles
    xform_fused_kernel<<<nTilesU + nTilesI, 256, 0, stream>>>(
        lx, lx2, ue, ie, Wg1, Wg2, bg1, bg2, W1, b1, part, nodes, meta, nTilesU);

    mlp_kernel<<<1024, 256, 0, stream>>>(part, cmapx, W2, b2, W3, b3,
                                         uid, iid, out, B);
}

// Round 16
// 200.907 us; speedup vs baseline: 2.3968x; 1.0354x over previous
//
#include <hip/hip_runtime.h>
#include <hip/hip_bf16.h>

#define USER_NUM 50000
#define ITEM_NUM 20000
#define NNODE    70000
#define DD       64
#define CHUNK    1024
#define NCHUNK   ((NNODE + CHUNK - 1) / CHUNK)   // 69
#define GROWS    (NNODE / 8)                     // 8750 rows per coarse group
#define APB      2048                            // append: edges per block
#define EPT      8                               // append: edges per thread
#define NS2      128                             // scatter2 stripes per group
#define NB3      16                              // hist3 blocks per group
#define T_CAP    32768                           // max touched slots (B=16384)
#define NCHUNK2  (T_CAP / CHUNK)                 // 32
#define GCAP     327680                          // per-group edge capacity
#define RT       16                              // xform tile rows (12KB LDS -> 8 blocks/CU)

__device__ __forceinline__ const float* feat_row(const float* __restrict__ ue,
                                                 const float* __restrict__ ie, int n) {
    return (n < USER_NUM) ? (ue + (size_t)n * DD)
                          : (ie + (size_t)(n - USER_NUM) * DD);
}

// ---- init: zero cnt2/tmask, seed gcur --------------------------------------

__global__ __launch_bounds__(256) void zero_kernel(int* __restrict__ cnt2,
                                                   int* __restrict__ tmask,
                                                   int* __restrict__ gcur) {
    const int tid    = blockIdx.x * 256 + (int)threadIdx.x;
    const int stride = gridDim.x * 256;
    for (int i = tid; i < T_CAP; i += stride) cnt2[i] = 0;
    for (int i = tid; i < NNODE; i += stride) tmask[i] = 0;
    if (tid < 8) gcur[tid] = tid * GCAP;
}

// ---- Touched-node marking --------------------------------------------------

__global__ __launch_bounds__(256) void mark_kernel(const int* __restrict__ uid,
                                                   const int* __restrict__ iid,
                                                   int* __restrict__ tmask, int B) {
    const int stride = gridDim.x * blockDim.x;
    for (int s = blockIdx.x * blockDim.x + threadIdx.x; s < B; s += stride) {
        tmask[uid[s]] = 1;                       // racing same-value stores: benign
        tmask[USER_NUM + iid[s]] = 1;
    }
}

// ---- Generic 3-phase scan pieces (domain size N as arg) --------------------

__global__ __launch_bounds__(256) void chunksum_kernel(const int* __restrict__ arr,
                                                       int* __restrict__ csum, int N) {
    __shared__ int red[4];
    const int c = blockIdx.x;
    const int t = threadIdx.x;
    int s = 0;
#pragma unroll
    for (int i = 0; i < 4; ++i) {
        const int idx = c * CHUNK + t + 256 * i;
        s += (idx < N) ? arr[idx] : 0;
    }
#pragma unroll
    for (int off = 32; off; off >>= 1) s += __shfl_down(s, off);
    if ((t & 63) == 0) red[t >> 6] = s;
    __syncthreads();
    if (t == 0) csum[c] = red[0] + red[1] + red[2] + red[3];
}

__global__ __launch_bounds__(128) void scan_small_kernel(const int* __restrict__ csum,
                                                         int* __restrict__ coff,
                                                         int NC) {
    __shared__ int s[128];
    const int t = threadIdx.x;
    const int v = (t < NC) ? csum[t] : 0;
    s[t] = v;
    __syncthreads();
    for (int off = 1; off < 128; off <<= 1) {
        const int val = s[t];
        const int add = (t >= off) ? s[t - off] : 0;
        __syncthreads();
        s[t] = val + add;
        __syncthreads();
    }
    if (t < NC) coff[t] = s[t] - v;
}

// Flags fill (NNODE domain): cmapx (slot or -1), nodes, meta[0]=T, meta[1]=Tu,
// gslot[g] = first slot of node-range group g (g=0..8).
__global__ __launch_bounds__(256) void fill_flags_kernel(
    const int* __restrict__ tmask, const int* __restrict__ coff,
    int* __restrict__ cmapx, int* __restrict__ nodes, int* __restrict__ meta,
    int* __restrict__ gslot) {
    __shared__ int sp[256];
    const int c  = blockIdx.x;
    const int t  = threadIdx.x;
    const int g0 = c * CHUNK + t * 4;
    int v[4];
#pragma unroll
    for (int i = 0; i < 4; ++i) v[i] = (g0 + i < NNODE) ? tmask[g0 + i] : 0;
    const int s = ((v[0] + v[1]) + (v[2] + v[3]));
    sp[t] = s;
    __syncthreads();
    for (int off = 1; off < 256; off <<= 1) {
        const int val = sp[t];
        const int add = (t >= off) ? sp[t - off] : 0;
        __syncthreads();
        sp[t] = val + add;
        __syncthreads();
    }
    int run = coff[c] + sp[t] - s;
#pragma unroll
    for (int i = 0; i < 4; ++i) {
        const int g = g0 + i;
        if (g < NNODE) {
            cmapx[g] = v[i] ? run : -1;
            if (v[i]) nodes[run] = g;
            if (g == USER_NUM) meta[1] = run;
            if (g % GROWS == 0) gslot[g / GROWS] = run;
            run += v[i];
        } else if (g == NNODE) {
            meta[0] = run;
            gslot[8] = run;
        }
    }
    if (g0 + 4 == NNODE) { meta[0] = run; gslot[8] = run; }
}

// Counts fill (N-domain, N multiple of 4): base + cursor; base[N]=total.
__global__ __launch_bounds__(256) void fill_kernel(const int* __restrict__ cnt,
                                                   const int* __restrict__ coff,
                                                   int* __restrict__ base,
                                                   int* __restrict__ cursor, int N) {
    __shared__ int sp[256];
    const int c  = blockIdx.x;
    const int t  = threadIdx.x;
    const int g0 = c * CHUNK + t * 4;
    int v[4];
#pragma unroll
    for (int i = 0; i < 4; ++i) v[i] = (g0 + i < N) ? cnt[g0 + i] : 0;
    const int s = ((v[0] + v[1]) + (v[2] + v[3]));
    sp[t] = s;
    __syncthreads();
    for (int off = 1; off < 256; off <<= 1) {
        const int val = sp[t];
        const int add = (t >= off) ? sp[t - off] : 0;
        __syncthreads();
        sp[t] = val + add;
        __syncthreads();
    }
    int run = coff[c] + sp[t] - s;
#pragma unroll
    for (int i = 0; i < 4; ++i) {
        const int g = g0 + i;
        if (g < N) {
            base[g]   = run;
            cursor[g] = run;
            run += v[i];
        }
    }
    if (g0 + 4 == N) base[N] = run;
}

// ---- Pass A: block-aggregated append of TOUCHED edges into 8 segments ------

__global__ __launch_bounds__(256) void append_kernel(
    const int* __restrict__ erow, const int* __restrict__ ecol,
    const float* __restrict__ eval, const int* __restrict__ cmapx,
    int* __restrict__ gcur, int* __restrict__ grow, int2* __restrict__ gpair,
    int E) {
    __shared__ int lcnt[8];
    __shared__ int lbase[8];
    const int t = threadIdx.x;
    if (t < 8) lcnt[t] = 0;
    __syncthreads();
    const int e0 = blockIdx.x * APB + t;
    int sl[EPT], c[EPT], gr[EPT], rk[EPT];
    float v[EPT];
#pragma unroll
    for (int i = 0; i < EPT; ++i) {
        const int e = e0 + 256 * i;
        gr[i] = -1;
        if (e < E) {
            const int r = erow[e];
            const int slot = cmapx[r];
            if (slot >= 0) {
                sl[i] = slot;
                c[i]  = ecol[e];
                v[i]  = eval[e];
                gr[i] = (r * 8) / NNODE;    // const div -> magic mul
                rk[i] = atomicAdd(&lcnt[gr[i]], 1);
            }
        }
    }
    __syncthreads();
    if (t < 8 && lcnt[t] > 0) lbase[t] = atomicAdd(&gcur[t], lcnt[t]);
    __syncthreads();
#pragma unroll
    for (int i = 0; i < EPT; ++i) {
        if (gr[i] >= 0) {
            const int pos = lbase[gr[i]] + rk[i];
            grow[pos]  = sl[i];             // compact slot
            gpair[pos] = make_int2(c[i], __float_as_int(v[i]));
        }
    }
}

// ---- Histogram: per-group LDS histogram over contiguous slot range ----------

__global__ __launch_bounds__(256) void hist3_kernel(const int* __restrict__ grow,
                                                    const int* __restrict__ gcur,
                                                    const int* __restrict__ gslot,
                                                    int* __restrict__ cnt2) {
    __shared__ int hloc[GROWS];
    const int g    = blockIdx.x & 7;
    const int rank = blockIdx.x >> 3;       // 0..NB3-1
    const int slo  = gslot[g];
    const int span = gslot[g + 1] - slo;
    for (int i = threadIdx.x; i < span; i += 256) hloc[i] = 0;
    __syncthreads();
    const int hi = gcur[g];
    for (int i = g * GCAP + rank * 256 + (int)threadIdx.x; i < hi; i += NB3 * 256)
        atomicAdd(&hloc[grow[i] - slo], 1);
    __syncthreads();
    for (int i = threadIdx.x; i < span; i += 256) {
        const int v = hloc[i];
        if (v) atomicAdd(&cnt2[slo + i], v);
    }
}

// ---- Pass B: per-group CSR scatter ------------------------------------------

__global__ __launch_bounds__(256) void scatter2_kernel(
    const int* __restrict__ grow, const int2* __restrict__ gpair,
    const int* __restrict__ gcur, int* __restrict__ cursor2,
    int2* __restrict__ epair) {
    const int g    = blockIdx.x & 7;
    const int rank = blockIdx.x >> 3;       // 0..NS2-1
    const int hi = gcur[g];
    for (int i = g * GCAP + rank * 256 + (int)threadIdx.x; i < hi; i += NS2 * 256) {
        const int slot = grow[i];
        const int pos = atomicAdd(&cursor2[slot], 1);
        epair[pos] = gpair[i];
    }
}

// ---- SpMM over compact touched rows ----------------------------------------

__global__ __launch_bounds__(256) void spmm_kernel(
    const float* __restrict__ ue, const float* __restrict__ ie,
    const int2* __restrict__ epair, const int* __restrict__ base2,
    const int* __restrict__ nodes, const int* __restrict__ meta,
    float* __restrict__ lx, float* __restrict__ lx2) {
    const int T = meta[0];
    const int lane = threadIdx.x & 63;
    int wv = (int)((blockIdx.x * blockDim.x + threadIdx.x) >> 6);
    wv = __builtin_amdgcn_readfirstlane(wv);
    const int nw = (int)((gridDim.x * blockDim.x) >> 6);
    for (int r = wv; r < T; r += nw) {
        const int jb = base2[r];
        const int je = base2[r + 1];
        float acc1 = 0.f, acc2 = 0.f;
        int j = jb;
        for (; j + 8 <= je; j += 8) {
            int2 p[8];
#pragma unroll
            for (int t = 0; t < 8; ++t) p[t] = epair[j + t];
            float f[8];
#pragma unroll
            for (int t = 0; t < 8; ++t) f[t] = feat_row(ue, ie, p[t].x)[lane];
#pragma unroll
            for (int t = 0; t < 8; ++t) {
                const float v = __int_as_float(p[t].y);
                acc1 = fmaf(v, f[t], acc1);
                acc2 = fmaf(v * f[t], f[t], acc2);
            }
        }
        for (; j + 4 <= je; j += 4) {
            int2 p[4];
#pragma unroll
            for (int t = 0; t < 4; ++t) p[t] = epair[j + t];
            float f[4];
#pragma unroll
            for (int t = 0; t < 4; ++t) f[t] = feat_row(ue, ie, p[t].x)[lane];
#pragma unroll
            for (int t = 0; t < 4; ++t) {
                const float v = __int_as_float(p[t].y);
                acc1 = fmaf(v, f[t], acc1);
                acc2 = fmaf(v * f[t], f[t], acc2);
            }
        }
        for (; j < je; ++j) {
            const int2 p = epair[j];
            const float f = feat_row(ue, ie, p.x)[lane];
            const float v = __int_as_float(p.y);
            acc1 = fmaf(v, f, acc1);
            acc2 = fmaf(v * f, f, acc2);
        }
        const int n = nodes[r];
        lx [(size_t)r * DD + lane] = acc1 + feat_row(ue, ie, n)[lane];
        lx2[(size_t)r * DD + lane] = acc2;
    }
}

// ---- Fused transform, combined user+item, 16-row tiles ----------------------
// blockIdx < nTilesU -> user tile; else item tile. Per tile:
//   phase1: h = lrelu(lx@Wg1 + lx2@Wg2 + bg1 + bg2)   -> kept in LDS
//   phase2: part = f@W1a + h@W1b (+ b1 for users)     -> global
// 12KB LDS, VGPR 64 -> 8 blocks/CU resident (32 waves/CU), 2048 blocks.

__global__ __launch_bounds__(256) void xform_fused_kernel(
    const float* __restrict__ lx, const float* __restrict__ lx2,
    const float* __restrict__ ue, const float* __restrict__ ie,
    const float* __restrict__ Wg1, const float* __restrict__ Wg2,
    const float* __restrict__ bg1, const float* __restrict__ bg2,
    const float* __restrict__ W1, const float* __restrict__ b1,
    float* __restrict__ part,
    const int* __restrict__ nodes, const int* __restrict__ meta, int nTilesU) {
    const int Tu = meta[1];
    const int T  = meta[0];
    const bool isU   = (int)blockIdx.x < nTilesU;
    const int tileIx = isU ? blockIdx.x : (blockIdx.x - nTilesU);
    const int start  = isU ? 0  : Tu;
    const int lim    = isU ? Tu : T;
    const int tb     = start + tileIx * RT;
    if (tb >= lim) return;
    const float* fb = isU ? ue : ie;

    __shared__ float sXa[RT * DD];      // phase1: lx      phase2: h
    __shared__ float sXb[RT * DD];      // phase1: lx2     phase2: f
    __shared__ float sP [RT * DD];
    const int t     = threadIdx.x;
    const int lane  = t & 63;
    const int w     = t >> 6;
    const int khalf = (w & 1) * 32;
    const int rhalf = (w >> 1) * (RT / 2);

    float wva[32], wvb[32];
#pragma unroll
    for (int k = 0; k < 32; ++k) {
        wva[k] = Wg1[(khalf + k) * DD + lane];
        wvb[k] = Wg2[(khalf + k) * DD + lane];
    }

    float4* sXav = (float4*)sXa;
    float4* sXbv = (float4*)sXb;
    float4* sPv  = (float4*)sP;
#pragma unroll
    for (int i = 0; i < RT / 16; ++i) {
        const int f4  = t + 256 * i;
        const int row = f4 >> 4;
        const int c   = f4 & 15;
        const int g   = min(tb + row, lim - 1);
        sXav[f4] = ((const float4*)(lx  + (size_t)g * DD))[c];
        sXbv[f4] = ((const float4*)(lx2 + (size_t)g * DD))[c];
        sPv[f4]  = make_float4(0.f, 0.f, 0.f, 0.f);
    }
    __syncthreads();

    // phase 1: h partials
#pragma unroll 2
    for (int r = 0; r < RT / 2; ++r) {
        const int row = rhalf + r;
        const float* ra = &sXa[row * DD + khalf];
        const float* rb = &sXb[row * DD + khalf];
        float o0 = 0.f, o1 = 0.f, o2 = 0.f, o3 = 0.f;
#pragma unroll
        for (int q = 0; q < 8; ++q) {
            const float4 qa = *(const float4*)(ra + 4 * q);
            const float4 qb = *(const float4*)(rb + 4 * q);
            o0 = fmaf(qa.x, wva[4 * q + 0], o0);
            o1 = fmaf(qa.y, wva[4 * q + 1], o1);
            o0 = fmaf(qa.z, wva[4 * q + 2], o0);
            o1 = fmaf(qa.w, wva[4 * q + 3], o1);
            o2 = fmaf(qb.x, wvb[4 * q + 0], o2);
            o3 = fmaf(qb.y, wvb[4 * q + 1], o3);
            o2 = fmaf(qb.z, wvb[4 * q + 2], o2);
            o3 = fmaf(qb.w, wvb[4 * q + 3], o3);
        }
        atomicAdd(&sP[row * DD + lane], (o0 + o1) + (o2 + o3));
    }
    __syncthreads();

    // epilogue 1: h = lrelu(sP + bg1 + bg2) -> sXa; reset sP; stage f -> sXb
#pragma unroll
    for (int i = 0; i < RT / 16; ++i) {
        const int f4  = t + 256 * i;
        const int row = f4 >> 4;
        const int c   = f4 & 15;
        float4 v = sPv[f4];
        const float4 ba = ((const float4*)bg1)[c];
        const float4 bb = ((const float4*)bg2)[c];
        v.x += ba.x + bb.x; v.y += ba.y + bb.y;
        v.z += ba.z + bb.z; v.w += ba.w + bb.w;
        v.x = (v.x > 0.f) ? v.x : 0.01f * v.x;
        v.y = (v.y > 0.f) ? v.y : 0.01f * v.y;
        v.z = (v.z > 0.f) ? v.z : 0.01f * v.z;
        v.w = (v.w > 0.f) ? v.w : 0.01f * v.w;
        sXav[f4] = v;                        // h
        sPv[f4]  = make_float4(0.f, 0.f, 0.f, 0.f);
        const int g = min(tb + row, lim - 1);
        int n = nodes[g];
        if (!isU) n -= USER_NUM;
        sXbv[f4] = ((const float4*)(fb + (size_t)n * DD))[c];   // f
    }

    // phase-2 weights: sXa(h) pairs W1b, sXb(f) pairs W1a
    const float* W1a = W1 + (isU ? 0 : 2 * DD * DD);
    const float* W1b = W1a + DD * DD;
#pragma unroll
    for (int k = 0; k < 32; ++k) {
        wva[k] = W1b[(khalf + k) * DD + lane];
        wvb[k] = W1a[(khalf + k) * DD + lane];
    }
    __syncthreads();

    // phase 2: part partials
#pragma unroll 2
    for (int r = 0; r < RT / 2; ++r) {
        const int row = rhalf + r;
        const float* ra = &sXa[row * DD + khalf];
        const float* rb = &sXb[row * DD + khalf];
        float o0 = 0.f, o1 = 0.f, o2 = 0.f, o3 = 0.f;
#pragma unroll
        for (int q = 0; q < 8; ++q) {
            const float4 qa = *(const float4*)(ra + 4 * q);
            const float4 qb = *(const float4*)(rb + 4 * q);
            o0 = fmaf(qa.x, wva[4 * q + 0], o0);
            o1 = fmaf(qa.y, wva[4 * q + 1], o1);
            o0 = fmaf(qa.z, wva[4 * q + 2], o0);
            o1 = fmaf(qa.w, wva[4 * q + 3], o1);
            o2 = fmaf(qb.x, wvb[4 * q + 0], o2);
            o3 = fmaf(qb.y, wvb[4 * q + 1], o3);
            o2 = fmaf(qb.z, wvb[4 * q + 2], o2);
            o3 = fmaf(qb.w, wvb[4 * q + 3], o3);
        }
        atomicAdd(&sP[row * DD + lane], (o0 + o1) + (o2 + o3));
    }
    __syncthreads();

    // epilogue 2: part = sP (+ b1 for users)
    float4* outv = (float4*)part;
#pragma unroll
    for (int i = 0; i < RT / 16; ++i) {
        const int f4  = t + 256 * i;
        const int row = f4 >> 4;
        const int c   = f4 & 15;
        const int g   = tb + row;
        float4 v = sPv[f4];
        if (isU) {
            const float4 b = ((const float4*)b1)[c];
            v.x += b.x; v.y += b.y; v.z += b.z; v.w += b.w;
        }
        if (g < lim) outv[(size_t)g * 16 + c] = v;
    }
}

// ---- Per-sample MLP: o1 = relu(part_u + part_i); layers 2,3 ----------------

__global__ __launch_bounds__(256) void mlp_kernel(
    const float* __restrict__ part, const int* __restrict__ cmapx,
    const float* __restrict__ W2, const float* __restrict__ b2,
    const float* __restrict__ W3, const float* __restrict__ b3,
    const int* __restrict__ uid, const int* __restrict__ iid,
    float* __restrict__ out, int B) {
    __shared__ float sW2[DD * 32];
    __shared__ float sW3[32];
    for (int i = threadIdx.x; i < DD * 32; i += 256) sW2[i] = W2[i];
    if (threadIdx.x < 32) sW3[threadIdx.x] = W3[threadIdx.x];
    __syncthreads();
    const int lane = threadIdx.x & 63;
    const int wave = (int)((blockIdx.x * blockDim.x + threadIdx.x) >> 6);
    const int nw   = (int)((gridDim.x * blockDim.x) >> 6);
    const float bias2 = b2[lane & 31];
    const float w3v   = sW3[lane & 31];
    const float bias3 = b3[0];
    for (int s = wave; s < B; s += nw) {
        const int su = cmapx[uid[s]];
        const int si = cmapx[USER_NUM + iid[s]];
        const float pu = part[(size_t)su * DD + lane];
        const float pi = part[(size_t)si * DD + lane];
        const float x  = pu + pi;
        const float o1 = (x > 0.f) ? x : 0.f;
        float acc_a = bias2, acc_b = 0.f;
#pragma unroll
        for (int k = 0; k < DD; k += 2) {
            acc_a = fmaf(__shfl(o1, k),     sW2[k * 32 + (lane & 31)],       acc_a);
            acc_b = fmaf(__shfl(o1, k + 1), sW2[(k + 1) * 32 + (lane & 31)], acc_b);
        }
        const float a2 = acc_a + acc_b;
        const float o2 = (a2 > 0.f) ? a2 : 0.f;
        float p = o2 * w3v;
        p += __shfl_xor(p, 1);
        p += __shfl_xor(p, 2);
        p += __shfl_xor(p, 4);
        p += __shfl_xor(p, 8);
        p += __shfl_xor(p, 16);
        if (lane == 0) out[s] = p + bias3;
    }
}

extern "C" void kernel_launch(void* const* d_in, const int* in_sizes, int n_in,
                              void* d_out, int out_size, void* d_ws, size_t ws_size,
                              hipStream_t stream) {
    const float* ue   = (const float*)d_in[0];
    const float* ie   = (const float*)d_in[1];
    const int*   erow = (const int*)d_in[2];
    const int*   ecol = (const int*)d_in[3];
    const float* evalp= (const float*)d_in[4];
    const float* Wg1  = (const float*)d_in[5];
    const float* bg1  = (const float*)d_in[6];
    const float* Wg2  = (const float*)d_in[7];
    const float* bg2  = (const float*)d_in[8];
    const float* W1   = (const float*)d_in[9];
    const float* b1   = (const float*)d_in[10];
    const float* W2   = (const float*)d_in[11];
    const float* b2   = (const float*)d_in[12];
    const float* W3   = (const float*)d_in[13];
    const float* b3   = (const float*)d_in[14];
    const int*   uid  = (const int*)d_in[15];
    const int*   iid  = (const int*)d_in[16];
    float* out = (float*)d_out;

    const int E = in_sizes[2];
    const int B = in_sizes[15];

    const int TU_MAX = (B < USER_NUM) ? B : USER_NUM;   // touched users <= B
    const int TI_MAX = (B < ITEM_NUM) ? B : ITEM_NUM;   // touched items <= B
    const int nTilesU = (TU_MAX + RT - 1) / RT;
    const int nTilesI = (TI_MAX + RT - 1) / RT;

    // workspace layout (~49.5 MB peak):
    //  [A: 32MB  lx|lx2|part (8MB each, compact T_CAP rows) + 8MB spare]
    //    - during CSR build, grow(10.5MB)+gpair(21MB) overlay region A
    //      (both dead before spmm writes lx/lx2)
    //  [B: epair 16MB]
    //  [C: misc ints ~1.2MB]
    char* ws = (char*)d_ws;
    const size_t ndc = (size_t)T_CAP * DD;              // 8MB per array
    float* lx    = (float*)ws;
    float* lx2   = lx + ndc;
    float* part  = lx2 + ndc;
    int*   grow  = (int*)ws;                            // 8*GCAP ints (10.5MB)
    int2*  gpair = (int2*)(ws + 11u * 1024 * 1024);     // 8*GCAP int2 (21MB)
    char*  tail  = ws + 32u * 1024 * 1024;
    int2*  epair = (int2*)tail;                         // E int2 = 16MB
    int*   mi    = (int*)(tail + (size_t)E * sizeof(int2));
    int*   cnt2    = mi;                                // T_CAP
    int*   cursor2 = cnt2 + T_CAP;                      // T_CAP
    int*   base2   = cursor2 + T_CAP;                   // T_CAP+1
    int*   tmask   = base2 + T_CAP + 1;                 // NNODE
    int*   cmapx   = tmask + NNODE;                     // NNODE
    int*   nodes   = cmapx + NNODE;                     // T_CAP
    int*   csum    = nodes + T_CAP;                     // 128
    int*   coff    = csum + 128;                        // 128
    int*   gcur    = coff + 128;                        // 8
    int*   meta    = gcur + 8;                          // [0]=T, [1]=Tu
    int*   gslot   = meta + 8;                          // 9 ints

    zero_kernel<<<512, 256, 0, stream>>>(cnt2, tmask, gcur);
    mark_kernel<<<(B + 255) / 256, 256, 0, stream>>>(uid, iid, tmask, B);
    chunksum_kernel<<<NCHUNK, 256, 0, stream>>>(tmask, csum, NNODE);
    scan_small_kernel<<<1, 128, 0, stream>>>(csum, coff, NCHUNK);
    fill_flags_kernel<<<NCHUNK, 256, 0, stream>>>(tmask, coff, cmapx, nodes,
                                                  meta, gslot);
    append_kernel<<<(E + APB - 1) / APB, 256, 0, stream>>>(
        erow, ecol, evalp, cmapx, gcur, grow, gpair, E);
    hist3_kernel<<<8 * NB3, 256, 0, stream>>>(grow, gcur, gslot, cnt2);
    chunksum_kernel<<<NCHUNK2, 256, 0, stream>>>(cnt2, csum, T_CAP);
    scan_small_kernel<<<1, 128, 0, stream>>>(csum, coff, NCHUNK2);
    fill_kernel<<<NCHUNK2, 256, 0, stream>>>(cnt2, coff, base2, cursor2, T_CAP);
    scatter2_kernel<<<8 * NS2, 256, 0, stream>>>(grow, gpair, gcur, cursor2, epair);
    spmm_kernel<<<4096, 256, 0, stream>>>(ue, ie, epair, base2, nodes, meta,
                                          lx, lx2);

    // fused transform: one launch covers user + item tiles
    xform_fused_kernel<<<nTilesU + nTilesI, 256, 0, stream>>>(
        lx, lx2, ue, ie, Wg1, Wg2, bg1, bg2, W1, b1, part, nodes, meta, nTilesU);

    mlp_kernel<<<1024, 256, 0, stream>>>(part, cmapx, W2, b2, W3, b3,
                                         uid, iid, out, B);
}